// Round 12
// baseline (442.504 us; speedup 1.0000x reference)
//
#include <hip/hip_runtime.h>
#include <hip/hip_bf16.h>

#define NN 100000
#define NE 1600000
#define NB_SCAN 391   // ceil(NN/256)
#define ETILES 12500  // NE/128
#define EGRID 768
#define NGRID 1024

typedef __attribute__((ext_vector_type(8))) short bfrag8;   // 8 bf16 (4 VGPRs) MFMA operand
typedef __attribute__((ext_vector_type(4))) float f32x4;    // MFMA accumulator
typedef __attribute__((ext_vector_type(8))) unsigned short us8;
typedef __attribute__((ext_vector_type(4))) unsigned int u32x4;

__device__ __forceinline__ unsigned short f2bf(float f) {
  unsigned int u = __float_as_uint(f);
  u += 0x7fffu + ((u >> 16) & 1u);   // RNE
  return (unsigned short)(u >> 16);
}

// packed 2x f32 -> 2x bf16 in one u32 (no builtin on gfx950 -> inline asm, RNE)
__device__ __forceinline__ unsigned int pk2(float a, float b) {
  unsigned int r;
  asm("v_cvt_pk_bf16_f32 %0, %1, %2" : "=v"(r) : "v"(a), "v"(b));
  return r;
}

__device__ __forceinline__ uint2 pk4(float v0, float v1, float v2, float v3) {
  return make_uint2(pk2(v0, v1), pk2(v2, v3));
}

__device__ __forceinline__ bfrag8 pack8(float4 a, float4 b) {
  union { u32x4 u; bfrag8 f; } c;
  c.u[0] = pk2(a.x, a.y); c.u[1] = pk2(a.z, a.w);
  c.u[2] = pk2(b.x, b.y); c.u[3] = pk2(b.z, b.w);
  return c.f;
}

__device__ __forceinline__ bfrag8 as_frag(us8 v) {
  union { us8 u; bfrag8 f; } c;
  c.u = v;
  return c.f;
}

__device__ __forceinline__ bfrag8 as_frag_u(u32x4 v) {
  union { u32x4 u; bfrag8 f; } c;
  c.u = v;
  return c.f;
}

__device__ __forceinline__ unsigned int sh(unsigned int v, int src) {
  return (unsigned int)__shfl((int)v, src, 64);
}

__device__ __forceinline__ float bl(unsigned int u) { return __uint_as_float(u << 16); }
__device__ __forceinline__ float bh(unsigned int u) { return __uint_as_float(u & 0xffff0000u); }

__device__ __forceinline__ f32x4 mfma16(bfrag8 a, bfrag8 b, f32x4 c) {
  return __builtin_amdgcn_mfma_f32_16x16x32_bf16(a, b, c, 0, 0, 0);
}

__device__ __forceinline__ void gload_lds16(const void* g, void* l) {
  __builtin_amdgcn_global_load_lds(
      (const __attribute__((address_space(1))) unsigned int*)g,
      (__attribute__((address_space(3))) unsigned int*)l, 16, 0, 0);
}

// ---------------- prep: cvt_atoms + count + pack_w in ONE launch ----------------
__global__ void prep(const float* __restrict__ atoms, unsigned short* __restrict__ atoms_bf,
                     const int* __restrict__ a2, int* __restrict__ cnt,
                     const float* __restrict__ We1, const float* __restrict__ We2,
                     const float* __restrict__ We3, const float* __restrict__ Wv1,
                     const float* __restrict__ Wv2, const float* __restrict__ Wv3,
                     unsigned short* __restrict__ wp) {
  const int b = blockIdx.x, tid = threadIdx.x;
  if (b < 3125) {                       // cvt_atoms: NN*32/4 = 800000 float4
    const int i = b * 256 + tid;
    float4 v = *(const float4*)(atoms + (size_t)i * 4);
    *(uint2*)(atoms_bf + (size_t)i * 4) = pk4(v.x, v.y, v.z, v.w);
  } else if (b < 3125 + 6250) {         // count
    const int e = (b - 3125) * 256 + tid;
    if (e < NE) atomicAdd(&cnt[a2[e]], 1);
  } else {                              // pack_w over flat table (40960 elems)
    const int i = (b - 9375) * 256 + tid;
    const float* src; int base, N;
    if (i < 12288)      { src = We1; base = 0;     N = 128; }
    else if (i < 20480) { src = We2; base = 12288; N = 64;  }
    else if (i < 22528) { src = We3; base = 20480; N = 32;  }
    else if (i < 30720) { src = Wv1; base = 22528; N = 128; }
    else if (i < 38912) { src = Wv2; base = 30720; N = 64;  }
    else                { src = Wv3; base = 38912; N = 32;  }
    const int il = i - base;
    const int j = il & 7, gc = il >> 3;
    const int c = gc % N, g = gc / N;
    wp[i] = f2bf(src[(g * 8 + j) * N + c]);
  }
}

// ---------------- CSR construction ----------------
__global__ void scan_blocks(const int* __restrict__ cnt, int* __restrict__ off,
                            int* __restrict__ bsum) {
  __shared__ int s[256];
  const int t = threadIdx.x;
  const int idx = blockIdx.x * 256 + t;
  int v = (idx < NN) ? cnt[idx] : 0;
  s[t] = v;
  __syncthreads();
  for (int d = 1; d < 256; d <<= 1) {
    int x = (t >= d) ? s[t - d] : 0;
    __syncthreads();
    s[t] += x;
    __syncthreads();
  }
  if (idx < NN) off[idx] = s[t] - v;          // exclusive within block
  if (t == 255) bsum[blockIdx.x] = s[255];
}

// finalize: each block computes its own base = sum(bsum[0..b-1])
__global__ void scan_finalize(int* __restrict__ off, const int* __restrict__ bsum,
                              int* __restrict__ cursor) {
  __shared__ int red[256];
  const int b = blockIdx.x, t = threadIdx.x;
  int s = 0;
  for (int k = t; k < b; k += 256) s += bsum[k];
  red[t] = s;
  __syncthreads();
  for (int d = 128; d > 0; d >>= 1) {
    if (t < d) red[t] += red[t + d];
    __syncthreads();
  }
  const int base = red[0];
  const int idx = b * 256 + t;
  if (idx < NN) {
    int o = off[idx] + base;
    off[idx] = o;
    cursor[idx] = o;
  }
  if (idx == 0) off[NN] = NE;
}

// mode 1: pos[e] = slot (coalesced write); mode 0: csr[slot] = e (scattered)
__global__ void fill_k(const int* __restrict__ a2, int* __restrict__ cursor,
                       int* __restrict__ buf, int mode) {
  int e = blockIdx.x * 256 + threadIdx.x;
  if (e < NE) {
    int p = atomicAdd(&cursor[a2[e]], 1);
    if (mode) buf[e] = p;
    else buf[p] = e;
  }
}

// ---------------- Edge kernel: persistent, barrier-free main loop (shuffle redistribution)
// Redistribution law (MFMA C -> next B-frag): dest lane (cl,q) word w comes from
// lane cl + ((q&1)*2 + (w>>1))*16, register rt_src = 2*ks + (q>>1), pair w&1.
template <int FAST>
__global__ __launch_bounds__(256, 3) void edge_kernel(
    const float* __restrict__ bonds, const int* __restrict__ a1p, const int* __restrict__ a2p,
    const unsigned short* __restrict__ atoms_bf,
    const float* __restrict__ be1, const float* __restrict__ be2, const float* __restrict__ be3,
    const unsigned short* __restrict__ wpack,
    float* __restrict__ new_bonds,
    const int* __restrict__ pos, unsigned short* __restrict__ nb_bf) {
  __shared__ unsigned short sW[22528];          // We1p[12288] We2p[8192] We3p[2048] = 45056 B
  __shared__ float sB1[128], sB2[64], sB3[32];  // total LDS ~45.9 KB -> 3 blocks/CU

  const int tid = threadIdx.x;
  const int lane = tid & 63, wv = tid >> 6;
  const int cl = lane & 15, q = lane >> 4;
  const int esub = wv * 32 + cl;                // + t*16
  const int srcA = cl + ((q & 1) << 5);
  const int srcB = srcA + 16;
  const bool hi = (lane & 32) != 0;             // q >= 2

  // ---- stage weights ONCE (async DMA) + biases
  {
    const char* src = (const char*)wpack;
    char* dst = (char*)sW;
#pragma unroll
    for (int i = 0; i < 11; ++i) {
      const int c = i * 4 + wv;
      gload_lds16(src + c * 1024 + lane * 16, dst + c * 1024);
    }
  }
  if (tid < 128) sB1[tid] = be1[tid];
  else if (tid < 192) sB2[tid - 128] = be2[tid - 128];
  else if (tid < 224) sB3[tid - 192] = be3[tid - 192];

  int tile = blockIdx.x;
  us8 ra1[2], ra2[2];      // atom bf16 frags (raw)
  float4 rb[2][2];         // bond f32 raw
  int ia1n[2], ia2n[2];    // indices for NEXT tile

  // ---- prologue: gather tile0; indices for tile0+G
#pragma unroll
  for (int t = 0; t < 2; ++t) {
    const int e = tile * 128 + esub + t * 16;
    const int ia1 = a1p[e], ia2 = a2p[e];
    ra1[t] = *(const us8*)(atoms_bf + (size_t)ia1 * 32 + q * 8);
    ra2[t] = *(const us8*)(atoms_bf + (size_t)ia2 * 32 + q * 8);
    const float* bp = bonds + (size_t)e * 32 + q * 8;
    rb[t][0] = *(const float4*)(bp);
    rb[t][1] = *(const float4*)(bp + 4);
  }
  {
    int tn = tile + EGRID; if (tn >= ETILES) tn = tile;
#pragma unroll
    for (int t = 0; t < 2; ++t) {
      const int e = tn * 128 + esub + t * 16;
      ia1n[t] = a1p[e]; ia2n[t] = a2p[e];
    }
  }
  __syncthreads();   // weights + biases staged (ONLY barrier in the kernel)

  for (; tile < ETILES; tile += EGRID) {
    // ---- convert current frags (frees ra/rb)
    bfrag8 xb0[2], xb1[2], xb2[2];
#pragma unroll
    for (int t = 0; t < 2; ++t) {
      xb0[t] = as_frag(ra1[t]);
      xb1[t] = as_frag(ra2[t]);
      xb2[t] = pack8(rb[t][0], rb[t][1]);
    }
    // ---- issue next tile's gathers (indices already resident), then next-next indices
    const int tn = (tile + EGRID < ETILES) ? tile + EGRID : tile;
#pragma unroll
    for (int t = 0; t < 2; ++t) {
      ra1[t] = *(const us8*)(atoms_bf + (size_t)ia1n[t] * 32 + q * 8);
      ra2[t] = *(const us8*)(atoms_bf + (size_t)ia2n[t] * 32 + q * 8);
      const int e = tn * 128 + esub + t * 16;
      const float* bp = bonds + (size_t)e * 32 + q * 8;
      rb[t][0] = *(const float4*)(bp);
      rb[t][1] = *(const float4*)(bp + 4);
    }
    {
      int tnn = tile + 2 * EGRID; if (tnn >= ETILES) tnn = tn;
#pragma unroll
      for (int t = 0; t < 2; ++t) {
        const int e = tnn * 128 + esub + t * 16;
        ia1n[t] = a1p[e]; ia2n[t] = a2p[e];
      }
    }

    // ---- GEMM1: h1^T[128][16x2]; pack into hp[t][rt][pair] (bf16 pairs, in-register)
    unsigned int hp[2][8][2];
#pragma unroll
    for (int rt = 0; rt < 8; ++rt) {
      const unsigned short* wa = &sW[(q * 128 + rt * 16 + cl) * 8];
      bfrag8 w0 = *(const bfrag8*)(wa);
      bfrag8 w1 = *(const bfrag8*)(wa + 4096);
      bfrag8 w2 = *(const bfrag8*)(wa + 8192);
      const int c0 = rt * 16 + q * 4;
#pragma unroll
      for (int t = 0; t < 2; ++t) {
        f32x4 acc = {0.f, 0.f, 0.f, 0.f};
        acc = mfma16(w0, xb0[t], acc);
        acc = mfma16(w1, xb1[t], acc);
        acc = mfma16(w2, xb2[t], acc);
        hp[t][rt][0] = pk2(fmaxf(acc[0] + sB1[c0 + 0], 0.f),
                           fmaxf(acc[1] + sB1[c0 + 1], 0.f));
        hp[t][rt][1] = pk2(fmaxf(acc[2] + sB1[c0 + 2], 0.f),
                           fmaxf(acc[3] + sB1[c0 + 3], 0.f));
      }
    }

    // ---- GEMM2: K=128, B-frags via shuffle redistribution ----
    f32x4 acc2[2][4];
#pragma unroll
    for (int t = 0; t < 2; ++t)
#pragma unroll
      for (int rt = 0; rt < 4; ++rt) acc2[t][rt] = (f32x4){0.f, 0.f, 0.f, 0.f};
#pragma unroll
    for (int ks = 0; ks < 4; ++ks) {
      bfrag8 hb[2];
#pragma unroll
      for (int t = 0; t < 2; ++t) {
        u32x4 bw;
        unsigned int x, y;
        x = sh(hp[t][2 * ks][0], srcA); y = sh(hp[t][2 * ks + 1][0], srcA); bw[0] = hi ? y : x;
        x = sh(hp[t][2 * ks][1], srcA); y = sh(hp[t][2 * ks + 1][1], srcA); bw[1] = hi ? y : x;
        x = sh(hp[t][2 * ks][0], srcB); y = sh(hp[t][2 * ks + 1][0], srcB); bw[2] = hi ? y : x;
        x = sh(hp[t][2 * ks][1], srcB); y = sh(hp[t][2 * ks + 1][1], srcB); bw[3] = hi ? y : x;
        hb[t] = as_frag_u(bw);
      }
#pragma unroll
      for (int rt = 0; rt < 4; ++rt) {
        bfrag8 w = *(const bfrag8*)&sW[12288 + ks * 2048 + (q * 64 + rt * 16 + cl) * 8];
#pragma unroll
        for (int t = 0; t < 2; ++t) acc2[t][rt] = mfma16(w, hb[t], acc2[t][rt]);
      }
    }
    // pack h2 -> hp2[t][rt][pair]
    unsigned int hp2[2][4][2];
#pragma unroll
    for (int rt = 0; rt < 4; ++rt) {
      const int c0 = rt * 16 + q * 4;
#pragma unroll
      for (int t = 0; t < 2; ++t) {
        hp2[t][rt][0] = pk2(fmaxf(acc2[t][rt][0] + sB2[c0 + 0], 0.f),
                            fmaxf(acc2[t][rt][1] + sB2[c0 + 1], 0.f));
        hp2[t][rt][1] = pk2(fmaxf(acc2[t][rt][2] + sB2[c0 + 2], 0.f),
                            fmaxf(acc2[t][rt][3] + sB2[c0 + 3], 0.f));
      }
    }

    // ---- GEMM3: K=64 ----
    f32x4 acc3[2][2];
#pragma unroll
    for (int t = 0; t < 2; ++t)
#pragma unroll
      for (int rt = 0; rt < 2; ++rt) acc3[t][rt] = (f32x4){0.f, 0.f, 0.f, 0.f};
#pragma unroll
    for (int ks = 0; ks < 2; ++ks) {
      bfrag8 gb[2];
#pragma unroll
      for (int t = 0; t < 2; ++t) {
        u32x4 bw;
        unsigned int x, y;
        x = sh(hp2[t][2 * ks][0], srcA); y = sh(hp2[t][2 * ks + 1][0], srcA); bw[0] = hi ? y : x;
        x = sh(hp2[t][2 * ks][1], srcA); y = sh(hp2[t][2 * ks + 1][1], srcA); bw[1] = hi ? y : x;
        x = sh(hp2[t][2 * ks][0], srcB); y = sh(hp2[t][2 * ks + 1][0], srcB); bw[2] = hi ? y : x;
        x = sh(hp2[t][2 * ks][1], srcB); y = sh(hp2[t][2 * ks + 1][1], srcB); bw[3] = hi ? y : x;
        gb[t] = as_frag_u(bw);
      }
#pragma unroll
      for (int rt = 0; rt < 2; ++rt) {
        bfrag8 w = *(const bfrag8*)&sW[20480 + ks * 1024 + (q * 32 + rt * 16 + cl) * 8];
#pragma unroll
        for (int t = 0; t < 2; ++t) acc3[t][rt] = mfma16(w, gb[t], acc3[t][rt]);
      }
    }

    // ---- epilogue: f32 store + (FAST) bf16 row scatter via shuffles ----
    unsigned int hp3[2][2][2];
#pragma unroll
    for (int rt = 0; rt < 2; ++rt) {
      const int c0 = rt * 16 + q * 4;
#pragma unroll
      for (int t = 0; t < 2; ++t) {
        float4 o;
        o.x = acc3[t][rt][0] + sB3[c0 + 0];
        o.y = acc3[t][rt][1] + sB3[c0 + 1];
        o.z = acc3[t][rt][2] + sB3[c0 + 2];
        o.w = acc3[t][rt][3] + sB3[c0 + 3];
        const int e = tile * 128 + esub + t * 16;
        *(float4*)(new_bonds + (size_t)e * 32 + c0) = o;
        if (FAST) {
          hp3[t][rt][0] = pk2(o.x, o.y);
          hp3[t][rt][1] = pk2(o.z, o.w);
        }
      }
    }
    if (FAST) {
#pragma unroll
      for (int t = 0; t < 2; ++t) {
        // 4 q-lanes cooperatively write edge (wv*32 + t*16 + cl)'s 64B row:
        // lane (cl,q) writes 16B chunk q. Word u: pair u&1, src q_src=(q&1)*2+(u>>1),
        // register rt_src = q>>1 (hi select).
        const int slot = pos[tile * 128 + wv * 32 + t * 16 + cl];
        u32x4 W;
        unsigned int x, y;
        x = sh(hp3[t][0][0], srcA); y = sh(hp3[t][1][0], srcA); W[0] = hi ? y : x;
        x = sh(hp3[t][0][1], srcA); y = sh(hp3[t][1][1], srcA); W[1] = hi ? y : x;
        x = sh(hp3[t][0][0], srcB); y = sh(hp3[t][1][0], srcB); W[2] = hi ? y : x;
        x = sh(hp3[t][0][1], srcB); y = sh(hp3[t][1][1], srcB); W[3] = hi ? y : x;
        *(u32x4*)(nb_bf + (size_t)slot * 32 + q * 8) = W;
      }
    }
  }
}

// ---------------- Gather (fast): sequential segmented mean over CSR-ordered bf16 rows ----
__global__ __launch_bounds__(256, 8) void gather_seq(
    const int* __restrict__ off, const unsigned short* __restrict__ nb_bf,
    unsigned short* __restrict__ mean_bf) {
  const int gt = blockIdx.x * 256 + threadIdx.x;   // NN*8
  const int n = gt >> 3, sl = gt & 7;              // 8 B slice (4 bf16) per thread
  const int o0 = off[n], o1 = off[n + 1];
  const int deg = o1 - o0;
  float s0 = 0.f, s1 = 0.f, s2 = 0.f, s3 = 0.f;
  const unsigned short* p = nb_bf + (size_t)o0 * 32 + sl * 4;
  int i = 0;
  for (; i + 1 < deg; i += 2) {
    uint2 a = *(const uint2*)(p);
    uint2 b = *(const uint2*)(p + 32);
    p += 64;
    s0 += bl(a.x) + bl(b.x); s1 += bh(a.x) + bh(b.x);
    s2 += bl(a.y) + bl(b.y); s3 += bh(a.y) + bh(b.y);
  }
  if (i < deg) {
    uint2 a = *(const uint2*)(p);
    s0 += bl(a.x); s1 += bh(a.x); s2 += bl(a.y); s3 += bh(a.y);
  }
  const float inv = 1.0f / fmaxf((float)deg, 1.0f);
  *(uint2*)(mean_bf + (size_t)n * 32 + sl * 4) =
      make_uint2(pk2(s0 * inv, s1 * inv), pk2(s2 * inv, s3 * inv));
}

// ---------------- Gather (fallback): random rows via csr ----------------
__global__ __launch_bounds__(256, 8) void gather_rand(
    const int* __restrict__ off, const int* __restrict__ csr,
    const float* __restrict__ new_bonds, float* __restrict__ mean_f32) {
  const int tid = blockIdx.x * 256 + threadIdx.x;   // NN*8
  const int n = tid >> 3, sl = tid & 7;             // 16 B slice per thread
  const int o0 = off[n], o1 = off[n + 1];
  float4 s0 = {0.f, 0.f, 0.f, 0.f}, s1 = {0.f, 0.f, 0.f, 0.f};
  int i = o0;
  for (; i + 1 < o1; i += 2) {
    const int ea = csr[i], eb = csr[i + 1];
    float4 a = *(const float4*)(new_bonds + (size_t)ea * 32 + sl * 4);
    float4 b = *(const float4*)(new_bonds + (size_t)eb * 32 + sl * 4);
    s0.x += a.x; s0.y += a.y; s0.z += a.z; s0.w += a.w;
    s1.x += b.x; s1.y += b.y; s1.z += b.z; s1.w += b.w;
  }
  if (i < o1) {
    const int ea = csr[i];
    float4 a = *(const float4*)(new_bonds + (size_t)ea * 32 + sl * 4);
    s0.x += a.x; s0.y += a.y; s0.z += a.z; s0.w += a.w;
  }
  const float inv = 1.0f / fmaxf((float)(o1 - o0), 1.0f);
  float4 m;
  m.x = (s0.x + s1.x) * inv;
  m.y = (s0.y + s1.y) * inv;
  m.z = (s0.z + s1.z) * inv;
  m.w = (s0.w + s1.w) * inv;
  *(float4*)(mean_f32 + (size_t)n * 32 + sl * 4) = m;
}

// ---------------- Node MLP: persistent, 64 nodes/tile, streaming inputs -------
// MODE 1: mean_src = bf16[NN*32]; MODE 0: mean_src = f32[NN*32]
template <int MODE>
__global__ __launch_bounds__(256, 4) void node_mlp(
    const unsigned short* __restrict__ atoms_bf,
    const float* __restrict__ bv1, const float* __restrict__ bv2, const float* __restrict__ bv3,
    const unsigned short* __restrict__ wpack,
    const void* __restrict__ mean_src, float* __restrict__ new_atoms) {
  __shared__ unsigned short sW[18432];          // Wv1p[8192] Wv2p[8192] Wv3p[2048]
  __shared__ float sB1[128], sB2[64], sB3[32];
  __shared__ unsigned short sV[64 * 72];        // v_in [64][64] pad->72; reused as h2
  __shared__ unsigned short sH1[64 * 136];

  const int tid = threadIdx.x;
  const int lane = tid & 63, wv = tid >> 6;
  const int cl = lane & 15, q = lane >> 4;
  const int nl = tid >> 2, l4 = tid & 3;

  {
    const uint4* src = (const uint4*)wpack;
    uint4* dst = (uint4*)sW;
#pragma unroll
    for (int i = 0; i < 9; ++i) dst[tid + i * 256] = src[tid + i * 256];
  }
  if (tid < 128) sB1[tid] = bv1[tid];
  if (tid < 64) sB2[tid] = bv2[tid];
  if (tid < 32) sB3[tid] = bv3[tid];

  for (int n0 = blockIdx.x * 64; n0 < NN; n0 += NGRID * 64) {
    __syncthreads();   // weights staged / previous tile's LDS reads complete

    // stage v tile: cols [0,32) = mean, [32,64) = atoms (bf16 copy)
    {
      const int n = n0 + nl;
      if (n < NN) {
        if (l4 < 2) {
          if (MODE == 1) {
            const unsigned short* mp = (const unsigned short*)mean_src + (size_t)n * 32 + l4 * 16;
            *(us8*)&sV[nl * 72 + l4 * 16] = *(const us8*)(mp);
            *(us8*)&sV[nl * 72 + l4 * 16 + 8] = *(const us8*)(mp + 8);
          } else {
            const float* sp = (const float*)mean_src + (size_t)n * 32 + l4 * 16;
            float4 a = *(const float4*)(sp);
            float4 b = *(const float4*)(sp + 4);
            float4 c = *(const float4*)(sp + 8);
            float4 d = *(const float4*)(sp + 12);
            uint4 o0, o1;
            o0.x = pk2(a.x, a.y); o0.y = pk2(a.z, a.w);
            o0.z = pk2(b.x, b.y); o0.w = pk2(b.z, b.w);
            o1.x = pk2(c.x, c.y); o1.y = pk2(c.z, c.w);
            o1.z = pk2(d.x, d.y); o1.w = pk2(d.z, d.w);
            *(uint4*)&sV[nl * 72 + l4 * 16] = o0;
            *(uint4*)&sV[nl * 72 + l4 * 16 + 8] = o1;
          }
        } else {
          const unsigned short* ap = atoms_bf + (size_t)n * 32 + (l4 - 2) * 16;
          *(us8*)&sV[nl * 72 + 32 + (l4 - 2) * 16] = *(const us8*)(ap);
          *(us8*)&sV[nl * 72 + 32 + (l4 - 2) * 16 + 8] = *(const us8*)(ap + 8);
        }
      } else {
        us8 z = {0, 0, 0, 0, 0, 0, 0, 0};
        *(us8*)&sV[nl * 72 + l4 * 16] = z;
        *(us8*)&sV[nl * 72 + l4 * 16 + 8] = z;
      }
    }
    __syncthreads();

    const int nt = wv * 16;
    const int ng = n0 + nt + cl;

    // ---- GEMM1: K=64 ----
    bfrag8 vb0 = *(const bfrag8*)&sV[(nt + cl) * 72 + q * 8];
    bfrag8 vb1 = *(const bfrag8*)&sV[(nt + cl) * 72 + 32 + q * 8];
#pragma unroll
    for (int rt = 0; rt < 8; ++rt) {
      f32x4 acc = {0.f, 0.f, 0.f, 0.f};
      acc = mfma16(*(const bfrag8*)&sW[(q * 128 + rt * 16 + cl) * 8], vb0, acc);
      acc = mfma16(*(const bfrag8*)&sW[4096 + (q * 128 + rt * 16 + cl) * 8], vb1, acc);
      const int c0 = rt * 16 + q * 4;
      uint2 hv = pk4(fmaxf(acc[0] + sB1[c0 + 0], 0.f),
                     fmaxf(acc[1] + sB1[c0 + 1], 0.f),
                     fmaxf(acc[2] + sB1[c0 + 2], 0.f),
                     fmaxf(acc[3] + sB1[c0 + 3], 0.f));
      *(uint2*)&sH1[(nt + cl) * 136 + c0] = hv;
    }
    __syncthreads();

    // ---- GEMM2: K=128 ----
    bfrag8 hb[4];
    {
      const unsigned short* hr = &sH1[(nt + cl) * 136 + q * 8];
#pragma unroll
      for (int ks = 0; ks < 4; ++ks) hb[ks] = *(const bfrag8*)(hr + ks * 32);
    }
    __syncthreads();   // h1 reads done -> overwrite sV as h2
#pragma unroll
    for (int rt = 0; rt < 4; ++rt) {
      f32x4 acc = {0.f, 0.f, 0.f, 0.f};
#pragma unroll
      for (int ks = 0; ks < 4; ++ks)
        acc = mfma16(*(const bfrag8*)&sW[8192 + ks * 2048 + (q * 64 + rt * 16 + cl) * 8], hb[ks], acc);
      const int c0 = rt * 16 + q * 4;
      uint2 hv = pk4(fmaxf(acc[0] + sB2[c0 + 0], 0.f),
                     fmaxf(acc[1] + sB2[c0 + 1], 0.f),
                     fmaxf(acc[2] + sB2[c0 + 2], 0.f),
                     fmaxf(acc[3] + sB2[c0 + 3], 0.f));
      *(uint2*)&sV[(nt + cl) * 72 + c0] = hv;   // reuse sV as h2
    }
    __syncthreads();

    // ---- GEMM3: K=64, no relu ----
    bfrag8 gb0 = *(const bfrag8*)&sV[(nt + cl) * 72 + q * 8];
    bfrag8 gb1 = *(const bfrag8*)&sV[(nt + cl) * 72 + 32 + q * 8];
    if (ng < NN) {
      float* outp = new_atoms + (size_t)ng * 32;
#pragma unroll
      for (int rt = 0; rt < 2; ++rt) {
        f32x4 acc = {0.f, 0.f, 0.f, 0.f};
        acc = mfma16(*(const bfrag8*)&sW[16384 + (q * 32 + rt * 16 + cl) * 8], gb0, acc);
        acc = mfma16(*(const bfrag8*)&sW[16384 + 1024 + (q * 32 + rt * 16 + cl) * 8], gb1, acc);
        const int c0 = rt * 16 + q * 4;
        float4 o;
        o.x = acc[0] + sB3[c0 + 0];
        o.y = acc[1] + sB3[c0 + 1];
        o.z = acc[2] + sB3[c0 + 2];
        o.w = acc[3] + sB3[c0 + 3];
        *(float4*)(outp + c0) = o;
      }
    }
  }
}

extern "C" void kernel_launch(void* const* d_in, const int* in_sizes, int n_in,
                              void* d_out, int out_size, void* d_ws, size_t ws_size,
                              hipStream_t stream) {
  const float* bonds = (const float*)d_in[0];
  const int* a1 = (const int*)d_in[1];
  const int* a2 = (const int*)d_in[2];
  const float* atoms = (const float*)d_in[3];
  const float* We1 = (const float*)d_in[4];
  const float* be1 = (const float*)d_in[5];
  const float* We2 = (const float*)d_in[6];
  const float* be2 = (const float*)d_in[7];
  const float* We3 = (const float*)d_in[8];
  const float* be3 = (const float*)d_in[9];
  const float* Wv1 = (const float*)d_in[10];
  const float* bv1 = (const float*)d_in[11];
  const float* Wv2 = (const float*)d_in[12];
  const float* bv2 = (const float*)d_in[13];
  const float* Wv3 = (const float*)d_in[14];
  const float* bv3 = (const float*)d_in[15];

  float* out = (float*)d_out;
  float* new_atoms = out;                       // [NN*32]; fallback: also mean_f32 scratch
  float* new_bonds = out + (size_t)NN * 32;     // [NE*32]

  char* ws = (char*)d_ws;
  int* cnt    = (int*)(ws + 0);                 // [NN], reused as fill cursor
  int* off    = (int*)(ws + 400000);            // [NN+1]
  int* bsum   = (int*)(ws + 800016);            // [512]
  unsigned short* wp = (unsigned short*)(ws + 802064);        // packed bf16 weights (81920 B)
  int* poscsr = (int*)(ws + 883984);            // [NE] pos (fast) or csr (fallback)
  unsigned short* atoms_bf = (unsigned short*)(ws + 7283984); // [NN*32] bf16 (6.4 MB)
  unsigned short* mean_bf  = (unsigned short*)(ws + 13683984); // [NN*32] bf16 (fast only)
  unsigned short* nb_bf    = (unsigned short*)(ws + 20083984); // [NE*32] bf16 (fast only)

  const int fast = (ws_size >= (size_t)122483984) ? 1 : 0;

  hipMemsetAsync(cnt, 0, (size_t)NN * 4, stream);

  prep<<<9535, 256, 0, stream>>>(atoms, atoms_bf, a2, cnt,
                                 We1, We2, We3, Wv1, Wv2, Wv3, wp);

  scan_blocks<<<NB_SCAN, 256, 0, stream>>>(cnt, off, bsum);
  scan_finalize<<<NB_SCAN, 256, 0, stream>>>(off, bsum, cnt);   // cursor := cnt
  fill_k<<<(NE + 255) / 256, 256, 0, stream>>>(a2, cnt, poscsr, fast);

  if (fast) {
    edge_kernel<1><<<EGRID, 256, 0, stream>>>(bonds, a1, a2, atoms_bf, be1, be2, be3, wp,
                                              new_bonds, poscsr, nb_bf);
    gather_seq<<<NN * 8 / 256, 256, 0, stream>>>(off, nb_bf, mean_bf);
    node_mlp<1><<<NGRID, 256, 0, stream>>>(atoms_bf, bv1, bv2, bv3, wp + 22528,
                                           mean_bf, new_atoms);
  } else {
    edge_kernel<0><<<EGRID, 256, 0, stream>>>(bonds, a1, a2, atoms_bf, be1, be2, be3, wp,
                                              new_bonds, nullptr, nullptr);
    gather_rand<<<NN * 8 / 256, 256, 0, stream>>>(off, poscsr, new_bonds, new_atoms);
    node_mlp<0><<<NGRID, 256, 0, stream>>>(atoms_bf, bv1, bv2, bv3, wp + 22528,
                                           new_atoms, new_atoms);
  }
}

// Round 13
// 399.522 us; speedup vs baseline: 1.1076x; 1.1076x over previous
//
#include <hip/hip_runtime.h>
#include <hip/hip_bf16.h>

#define NN 100000
#define NE 1600000
#define NB_SCAN 391   // ceil(NN/256)
#define ETILES 12500  // NE/128
#define EGRID 512
#define NGRID 1024

typedef __attribute__((ext_vector_type(8))) short bfrag8;   // 8 bf16 (4 VGPRs) MFMA operand
typedef __attribute__((ext_vector_type(4))) float f32x4;    // MFMA accumulator
typedef __attribute__((ext_vector_type(8))) unsigned short us8;
typedef __attribute__((ext_vector_type(4))) unsigned int u32x4;

__device__ __forceinline__ unsigned short f2bf(float f) {
  unsigned int u = __float_as_uint(f);
  u += 0x7fffu + ((u >> 16) & 1u);   // RNE
  return (unsigned short)(u >> 16);
}

// packed 2x f32 -> 2x bf16 in one u32 (no builtin on gfx950 -> inline asm, RNE)
__device__ __forceinline__ unsigned int pk2(float a, float b) {
  unsigned int r;
  asm("v_cvt_pk_bf16_f32 %0, %1, %2" : "=v"(r) : "v"(a), "v"(b));
  return r;
}

__device__ __forceinline__ uint2 pk4(float v0, float v1, float v2, float v3) {
  return make_uint2(pk2(v0, v1), pk2(v2, v3));
}

__device__ __forceinline__ bfrag8 pack8(float4 a, float4 b) {
  union { u32x4 u; bfrag8 f; } c;
  c.u[0] = pk2(a.x, a.y); c.u[1] = pk2(a.z, a.w);
  c.u[2] = pk2(b.x, b.y); c.u[3] = pk2(b.z, b.w);
  return c.f;
}

__device__ __forceinline__ bfrag8 as_frag(us8 v) {
  union { us8 u; bfrag8 f; } c;
  c.u = v;
  return c.f;
}

__device__ __forceinline__ float b2f(unsigned short u) {
  return __uint_as_float((unsigned int)u << 16);
}

__device__ __forceinline__ float bl(unsigned int u) { return __uint_as_float(u << 16); }
__device__ __forceinline__ float bh(unsigned int u) { return __uint_as_float(u & 0xffff0000u); }

__device__ __forceinline__ f32x4 mfma16(bfrag8 a, bfrag8 b, f32x4 c) {
  return __builtin_amdgcn_mfma_f32_16x16x32_bf16(a, b, c, 0, 0, 0);
}

__device__ __forceinline__ void gload_lds16(const void* g, void* l) {
  __builtin_amdgcn_global_load_lds(
      (const __attribute__((address_space(1))) unsigned int*)g,
      (__attribute__((address_space(3))) unsigned int*)l, 16, 0, 0);
}

// ---------------- prep: cvt_atoms + count + pack_w in ONE launch ----------------
__global__ void prep(const float* __restrict__ atoms, unsigned short* __restrict__ atoms_bf,
                     const int* __restrict__ a2, int* __restrict__ cnt,
                     const float* __restrict__ We1, const float* __restrict__ We2,
                     const float* __restrict__ We3, const float* __restrict__ Wv1,
                     const float* __restrict__ Wv2, const float* __restrict__ Wv3,
                     unsigned short* __restrict__ wp) {
  const int b = blockIdx.x, tid = threadIdx.x;
  if (b < 3125) {                       // cvt_atoms: NN*32/4 = 800000 float4
    const int i = b * 256 + tid;
    float4 v = *(const float4*)(atoms + (size_t)i * 4);
    *(uint2*)(atoms_bf + (size_t)i * 4) = pk4(v.x, v.y, v.z, v.w);
  } else if (b < 3125 + 6250) {         // count
    const int e = (b - 3125) * 256 + tid;
    if (e < NE) atomicAdd(&cnt[a2[e]], 1);
  } else {                              // pack_w over flat table (40960 elems)
    const int i = (b - 9375) * 256 + tid;
    const float* src; int base, N;
    if (i < 12288)      { src = We1; base = 0;     N = 128; }
    else if (i < 20480) { src = We2; base = 12288; N = 64;  }
    else if (i < 22528) { src = We3; base = 20480; N = 32;  }
    else if (i < 30720) { src = Wv1; base = 22528; N = 128; }
    else if (i < 38912) { src = Wv2; base = 30720; N = 64;  }
    else                { src = Wv3; base = 38912; N = 32;  }
    const int il = i - base;
    const int j = il & 7, gc = il >> 3;
    const int c = gc % N, g = gc / N;
    wp[i] = f2bf(src[(g * 8 + j) * N + c]);
  }
}

// ---------------- CSR construction ----------------
__global__ void scan_blocks(const int* __restrict__ cnt, int* __restrict__ off,
                            int* __restrict__ bsum) {
  __shared__ int s[256];
  const int t = threadIdx.x;
  const int idx = blockIdx.x * 256 + t;
  int v = (idx < NN) ? cnt[idx] : 0;
  s[t] = v;
  __syncthreads();
  for (int d = 1; d < 256; d <<= 1) {
    int x = (t >= d) ? s[t - d] : 0;
    __syncthreads();
    s[t] += x;
    __syncthreads();
  }
  if (idx < NN) off[idx] = s[t] - v;          // exclusive within block
  if (t == 255) bsum[blockIdx.x] = s[255];
}

// finalize: each block computes its own base = sum(bsum[0..b-1])
__global__ void scan_finalize(int* __restrict__ off, const int* __restrict__ bsum,
                              int* __restrict__ cursor) {
  __shared__ int red[256];
  const int b = blockIdx.x, t = threadIdx.x;
  int s = 0;
  for (int k = t; k < b; k += 256) s += bsum[k];
  red[t] = s;
  __syncthreads();
  for (int d = 128; d > 0; d >>= 1) {
    if (t < d) red[t] += red[t + d];
    __syncthreads();
  }
  const int base = red[0];
  const int idx = b * 256 + t;
  if (idx < NN) {
    int o = off[idx] + base;
    off[idx] = o;
    cursor[idx] = o;
  }
  if (idx == 0) off[NN] = NE;
}

// mode 1: pos[e] = slot (coalesced write); mode 0: csr[slot] = e (scattered)
__global__ void fill_k(const int* __restrict__ a2, int* __restrict__ cursor,
                       int* __restrict__ buf, int mode) {
  int e = blockIdx.x * 256 + threadIdx.x;
  if (e < NE) {
    int p = atomicAdd(&cursor[a2[e]], 1);
    if (mode) buf[e] = p;
    else buf[p] = e;
  }
}

// ---------------- Edge kernel: persistent, 128 edges/tile, 1-tile pipeline (R11 form) ----
// FAST=1: also emit bf16 rows to nb_bf[pos[e]] via LDS restage + 64B-contiguous row writes.
template <int FAST>
__global__ __launch_bounds__(256, 2) void edge_kernel(
    const float* __restrict__ bonds, const int* __restrict__ a1p, const int* __restrict__ a2p,
    const unsigned short* __restrict__ atoms_bf,
    const float* __restrict__ be1, const float* __restrict__ be2, const float* __restrict__ be3,
    const unsigned short* __restrict__ wpack,
    float* __restrict__ new_bonds,
    const int* __restrict__ pos, unsigned short* __restrict__ nb_bf) {
  __shared__ unsigned short sW[22528];          // We1p[12288] We2p[8192] We3p[2048] = 45056 B
  __shared__ float sB1[128], sB2[64], sB3[32];
  __shared__ unsigned short sH1[128 * 136];     // h1 [128][128] pad->136; aliased: h2 [128][72] in
                                                // [0,9216); out-stage [128][40] in [9216,14336)

  const int tid = threadIdx.x;
  const int lane = tid & 63, wv = tid >> 6;
  const int cl = lane & 15, q = lane >> 4;
  const int esub = wv * 32 + cl;                // + t*16

  // ---- stage weights ONCE (async DMA) + biases
  {
    const char* src = (const char*)wpack;
    char* dst = (char*)sW;
#pragma unroll
    for (int i = 0; i < 11; ++i) {
      const int c = i * 4 + wv;
      gload_lds16(src + c * 1024 + lane * 16, dst + c * 1024);
    }
  }
  if (tid < 128) sB1[tid] = be1[tid];
  else if (tid < 192) sB2[tid - 128] = be2[tid - 128];
  else if (tid < 224) sB3[tid - 192] = be3[tid - 192];

  int tile = blockIdx.x;
  us8 ra1[2], ra2[2];      // atom bf16 frags (raw)
  float4 rb[2][2];         // bond f32 raw
  int ia1n[2], ia2n[2];    // indices for NEXT tile
  int slotc = 0;           // CSR slot for this thread's row (tid<128), current tile

  // ---- prologue: gather tile0; indices for tile0+G
#pragma unroll
  for (int t = 0; t < 2; ++t) {
    const int e = tile * 128 + esub + t * 16;
    const int ia1 = a1p[e], ia2 = a2p[e];
    ra1[t] = *(const us8*)(atoms_bf + (size_t)ia1 * 32 + q * 8);
    ra2[t] = *(const us8*)(atoms_bf + (size_t)ia2 * 32 + q * 8);
    const float* bp = bonds + (size_t)e * 32 + q * 8;
    rb[t][0] = *(const float4*)(bp);
    rb[t][1] = *(const float4*)(bp + 4);
  }
  if (FAST && tid < 128) slotc = pos[tile * 128 + tid];
  {
    int tn = tile + EGRID; if (tn >= ETILES) tn = tile;
#pragma unroll
    for (int t = 0; t < 2; ++t) {
      const int e = tn * 128 + esub + t * 16;
      ia1n[t] = a1p[e]; ia2n[t] = a2p[e];
    }
  }
  __syncthreads();   // weights + biases staged

  for (; tile < ETILES; tile += EGRID) {
    // ---- convert current frags (frees ra/rb)
    bfrag8 xb0[2], xb1[2], xb2[2];
#pragma unroll
    for (int t = 0; t < 2; ++t) {
      xb0[t] = as_frag(ra1[t]);
      xb1[t] = as_frag(ra2[t]);
      xb2[t] = pack8(rb[t][0], rb[t][1]);
    }
    // ---- issue next tile's gathers (indices already resident), then next-next indices
    const int tn = (tile + EGRID < ETILES) ? tile + EGRID : tile;
#pragma unroll
    for (int t = 0; t < 2; ++t) {
      ra1[t] = *(const us8*)(atoms_bf + (size_t)ia1n[t] * 32 + q * 8);
      ra2[t] = *(const us8*)(atoms_bf + (size_t)ia2n[t] * 32 + q * 8);
      const int e = tn * 128 + esub + t * 16;
      const float* bp = bonds + (size_t)e * 32 + q * 8;
      rb[t][0] = *(const float4*)(bp);
      rb[t][1] = *(const float4*)(bp + 4);
    }
    int slotn = 0;
    if (FAST && tid < 128) slotn = pos[tn * 128 + tid];
    {
      int tnn = tile + 2 * EGRID; if (tnn >= ETILES) tnn = tn;
#pragma unroll
      for (int t = 0; t < 2; ++t) {
        const int e = tnn * 128 + esub + t * 16;
        ia1n[t] = a1p[e]; ia2n[t] = a2p[e];
      }
    }

    // ---- GEMM1: h1^T[128][16x2] = We1^T[128x96] @ x^T ----
#pragma unroll
    for (int rt = 0; rt < 8; ++rt) {
      const unsigned short* wa = &sW[(q * 128 + rt * 16 + cl) * 8];
      bfrag8 w0 = *(const bfrag8*)(wa);
      bfrag8 w1 = *(const bfrag8*)(wa + 4096);
      bfrag8 w2 = *(const bfrag8*)(wa + 8192);
      f32x4 acc[2];
      acc[0] = (f32x4){0.f, 0.f, 0.f, 0.f};
      acc[1] = (f32x4){0.f, 0.f, 0.f, 0.f};
#pragma unroll
      for (int t = 0; t < 2; ++t) {
        acc[t] = mfma16(w0, xb0[t], acc[t]);
        acc[t] = mfma16(w1, xb1[t], acc[t]);
        acc[t] = mfma16(w2, xb2[t], acc[t]);
      }
      const int c0 = rt * 16 + q * 4;
#pragma unroll
      for (int t = 0; t < 2; ++t) {
        uint2 hv = pk4(fmaxf(acc[t][0] + sB1[c0 + 0], 0.f),
                       fmaxf(acc[t][1] + sB1[c0 + 1], 0.f),
                       fmaxf(acc[t][2] + sB1[c0 + 2], 0.f),
                       fmaxf(acc[t][3] + sB1[c0 + 3], 0.f));
        *(uint2*)&sH1[(esub + t * 16) * 136 + c0] = hv;
      }
    }
    __syncthreads();   // h1 complete

    // ---- GEMM2: h2^T[64][16x2] = We2^T[64x128] @ h1^T ----
    bfrag8 hb[4][2];
#pragma unroll
    for (int t = 0; t < 2; ++t) {
      const unsigned short* hr = &sH1[(esub + t * 16) * 136 + q * 8];
#pragma unroll
      for (int ks = 0; ks < 4; ++ks) hb[ks][t] = *(const bfrag8*)(hr + ks * 32);
    }
    __syncthreads();   // h1 reads done -> safe to overwrite as h2 / out-stage

    unsigned short* sH2 = sH1;   // stride 72, [0,9216)
#pragma unroll
    for (int rt = 0; rt < 4; ++rt) {
      f32x4 acc[2];
      acc[0] = (f32x4){0.f, 0.f, 0.f, 0.f};
      acc[1] = (f32x4){0.f, 0.f, 0.f, 0.f};
#pragma unroll
      for (int ks = 0; ks < 4; ++ks) {
        bfrag8 w = *(const bfrag8*)&sW[12288 + ks * 2048 + (q * 64 + rt * 16 + cl) * 8];
#pragma unroll
        for (int t = 0; t < 2; ++t) acc[t] = mfma16(w, hb[ks][t], acc[t]);
      }
      const int c0 = rt * 16 + q * 4;
#pragma unroll
      for (int t = 0; t < 2; ++t) {
        uint2 hv = pk4(fmaxf(acc[t][0] + sB2[c0 + 0], 0.f),
                       fmaxf(acc[t][1] + sB2[c0 + 1], 0.f),
                       fmaxf(acc[t][2] + sB2[c0 + 2], 0.f),
                       fmaxf(acc[t][3] + sB2[c0 + 3], 0.f));
        *(uint2*)&sH2[(esub + t * 16) * 72 + c0] = hv;
      }
    }
    __syncthreads();   // h2 complete

    // ---- GEMM3: out^T[32][16x2] = We3^T[32x64] @ h2^T ----
    bfrag8 gb0[2], gb1[2];
#pragma unroll
    for (int t = 0; t < 2; ++t) {
      const unsigned short* hr = &sH2[(esub + t * 16) * 72 + q * 8];
      gb0[t] = *(const bfrag8*)(hr);
      gb1[t] = *(const bfrag8*)(hr + 32);
    }
    unsigned short* sOut = sH1 + 9216;   // [128][40] shorts, dead region above h2
#pragma unroll
    for (int rt = 0; rt < 2; ++rt) {
      bfrag8 w0 = *(const bfrag8*)&sW[20480 + (q * 32 + rt * 16 + cl) * 8];
      bfrag8 w1 = *(const bfrag8*)&sW[20480 + 1024 + (q * 32 + rt * 16 + cl) * 8];
      const int c0 = rt * 16 + q * 4;
#pragma unroll
      for (int t = 0; t < 2; ++t) {
        f32x4 acc = {0.f, 0.f, 0.f, 0.f};
        acc = mfma16(w0, gb0[t], acc);
        acc = mfma16(w1, gb1[t], acc);
        const int e = tile * 128 + esub + t * 16;
        float4 o;
        o.x = acc[0] + sB3[c0 + 0];
        o.y = acc[1] + sB3[c0 + 1];
        o.z = acc[2] + sB3[c0 + 2];
        o.w = acc[3] + sB3[c0 + 3];
        *(float4*)(new_bonds + (size_t)e * 32 + c0) = o;
        if (FAST) {
          *(uint2*)&sOut[(esub + t * 16) * 40 + c0] =
              make_uint2(pk2(o.x, o.y), pk2(o.z, o.w));
        }
      }
    }
    if (FAST) {
      __syncthreads();   // out-stage complete (rows span waves)
      if (tid < 128) {
        const u32x4* src = (const u32x4*)&sOut[tid * 40];
        u32x4* dst = (u32x4*)(nb_bf + (size_t)slotc * 32);
#pragma unroll
        for (int k = 0; k < 4; ++k) dst[k] = src[k];   // 64B contiguous per thread
      }
      slotc = slotn;
    }
    __syncthreads();   // all LDS reads done -> next tile may overwrite sH1/sH2/sOut
  }
}

// ---------------- Gather (fallback): random rows via csr ----------------
__global__ __launch_bounds__(256, 8) void gather_rand(
    const int* __restrict__ off, const int* __restrict__ csr,
    const float* __restrict__ new_bonds, float* __restrict__ mean_f32) {
  const int tid = blockIdx.x * 256 + threadIdx.x;   // NN*8
  const int n = tid >> 3, sl = tid & 7;             // 16 B slice per thread
  const int o0 = off[n], o1 = off[n + 1];
  float4 s0 = {0.f, 0.f, 0.f, 0.f}, s1 = {0.f, 0.f, 0.f, 0.f};
  int i = o0;
  for (; i + 1 < o1; i += 2) {
    const int ea = csr[i], eb = csr[i + 1];
    float4 a = *(const float4*)(new_bonds + (size_t)ea * 32 + sl * 4);
    float4 b = *(const float4*)(new_bonds + (size_t)eb * 32 + sl * 4);
    s0.x += a.x; s0.y += a.y; s0.z += a.z; s0.w += a.w;
    s1.x += b.x; s1.y += b.y; s1.z += b.z; s1.w += b.w;
  }
  if (i < o1) {
    const int ea = csr[i];
    float4 a = *(const float4*)(new_bonds + (size_t)ea * 32 + sl * 4);
    s0.x += a.x; s0.y += a.y; s0.z += a.z; s0.w += a.w;
  }
  const float inv = 1.0f / fmaxf((float)(o1 - o0), 1.0f);
  float4 m;
  m.x = (s0.x + s1.x) * inv;
  m.y = (s0.y + s1.y) * inv;
  m.z = (s0.z + s1.z) * inv;
  m.w = (s0.w + s1.w) * inv;
  *(float4*)(mean_f32 + (size_t)n * 32 + sl * 4) = m;
}

// ---------------- Node MLP: persistent, 64 nodes/tile ----------------
// MODE 1: fused segmented mean over CSR-ordered nb_bf (sequential reads per node).
// MODE 0: mean_f32 precomputed by gather_rand.
template <int MODE>
__global__ __launch_bounds__(256, 4) void node_mlp(
    const unsigned short* __restrict__ atoms_bf,
    const float* __restrict__ bv1, const float* __restrict__ bv2, const float* __restrict__ bv3,
    const unsigned short* __restrict__ wpack,
    const int* __restrict__ off, const unsigned short* __restrict__ nb_bf,
    const float* __restrict__ mean_f32, float* __restrict__ new_atoms) {
  __shared__ unsigned short sW[18432];          // Wv1p[8192] Wv2p[8192] Wv3p[2048]
  __shared__ float sB1[128], sB2[64], sB3[32];
  __shared__ unsigned short sV[64 * 72];        // v_in [64][64] pad->72; reused as h2
  __shared__ unsigned short sH1[64 * 136];

  const int tid = threadIdx.x;
  const int lane = tid & 63, wv = tid >> 6;
  const int cl = lane & 15, q = lane >> 4;
  const int nl = tid >> 2, l4 = tid & 3;

  {
    const uint4* src = (const uint4*)wpack;
    uint4* dst = (uint4*)sW;
#pragma unroll
    for (int i = 0; i < 9; ++i) dst[tid + i * 256] = src[tid + i * 256];
  }
  if (tid < 128) sB1[tid] = bv1[tid];
  if (tid < 64) sB2[tid] = bv2[tid];
  if (tid < 32) sB3[tid] = bv3[tid];

  for (int n0 = blockIdx.x * 64; n0 < NN; n0 += NGRID * 64) {
    __syncthreads();   // weights staged / previous tile's LDS reads complete

    // stage v tile: cols [0,32) = mean, [32,64) = atoms (bf16 copy)
    {
      const int n = n0 + nl;
      if (n < NN) {
        if (l4 < 2) {
          if (MODE == 1) {
            // fused segmented mean: this thread owns 16 bf16 cols (l4*16 .. +15)
            const int o0 = off[n], o1 = off[n + 1];
            float s[16];
#pragma unroll
            for (int j = 0; j < 16; ++j) s[j] = 0.f;
            const unsigned short* p = nb_bf + (size_t)o0 * 32 + l4 * 16;
            for (int i = o0; i < o1; ++i, p += 32) {
              us8 a = *(const us8*)(p);
              us8 b = *(const us8*)(p + 8);
#pragma unroll
              for (int j = 0; j < 8; ++j) {
                s[j]     += b2f((unsigned short)a[j]);
                s[8 + j] += b2f((unsigned short)b[j]);
              }
            }
            const float inv = 1.0f / fmaxf((float)(o1 - o0), 1.0f);
            uint4 m0, m1;
            m0.x = pk2(s[0] * inv, s[1] * inv);  m0.y = pk2(s[2] * inv, s[3] * inv);
            m0.z = pk2(s[4] * inv, s[5] * inv);  m0.w = pk2(s[6] * inv, s[7] * inv);
            m1.x = pk2(s[8] * inv, s[9] * inv);  m1.y = pk2(s[10] * inv, s[11] * inv);
            m1.z = pk2(s[12] * inv, s[13] * inv); m1.w = pk2(s[14] * inv, s[15] * inv);
            *(uint4*)&sV[nl * 72 + l4 * 16] = m0;
            *(uint4*)&sV[nl * 72 + l4 * 16 + 8] = m1;
          } else {
            const float* sp = mean_f32 + (size_t)n * 32 + l4 * 16;
            float4 a = *(const float4*)(sp);
            float4 b = *(const float4*)(sp + 4);
            float4 c = *(const float4*)(sp + 8);
            float4 d = *(const float4*)(sp + 12);
            uint4 o0v, o1v;
            o0v.x = pk2(a.x, a.y); o0v.y = pk2(a.z, a.w);
            o0v.z = pk2(b.x, b.y); o0v.w = pk2(b.z, b.w);
            o1v.x = pk2(c.x, c.y); o1v.y = pk2(c.z, c.w);
            o1v.z = pk2(d.x, d.y); o1v.w = pk2(d.z, d.w);
            *(uint4*)&sV[nl * 72 + l4 * 16] = o0v;
            *(uint4*)&sV[nl * 72 + l4 * 16 + 8] = o1v;
          }
        } else {
          const unsigned short* ap = atoms_bf + (size_t)n * 32 + (l4 - 2) * 16;
          *(us8*)&sV[nl * 72 + 32 + (l4 - 2) * 16] = *(const us8*)(ap);
          *(us8*)&sV[nl * 72 + 32 + (l4 - 2) * 16 + 8] = *(const us8*)(ap + 8);
        }
      } else {
        us8 z = {0, 0, 0, 0, 0, 0, 0, 0};
        *(us8*)&sV[nl * 72 + l4 * 16] = z;
        *(us8*)&sV[nl * 72 + l4 * 16 + 8] = z;
      }
    }
    __syncthreads();

    const int nt = wv * 16;
    const int ng = n0 + nt + cl;

    // ---- GEMM1: K=64 ----
    bfrag8 vb0 = *(const bfrag8*)&sV[(nt + cl) * 72 + q * 8];
    bfrag8 vb1 = *(const bfrag8*)&sV[(nt + cl) * 72 + 32 + q * 8];
#pragma unroll
    for (int rt = 0; rt < 8; ++rt) {
      f32x4 acc = {0.f, 0.f, 0.f, 0.f};
      acc = mfma16(*(const bfrag8*)&sW[(q * 128 + rt * 16 + cl) * 8], vb0, acc);
      acc = mfma16(*(const bfrag8*)&sW[4096 + (q * 128 + rt * 16 + cl) * 8], vb1, acc);
      const int c0 = rt * 16 + q * 4;
      uint2 hv = pk4(fmaxf(acc[0] + sB1[c0 + 0], 0.f),
                     fmaxf(acc[1] + sB1[c0 + 1], 0.f),
                     fmaxf(acc[2] + sB1[c0 + 2], 0.f),
                     fmaxf(acc[3] + sB1[c0 + 3], 0.f));
      *(uint2*)&sH1[(nt + cl) * 136 + c0] = hv;
    }
    __syncthreads();

    // ---- GEMM2: K=128 ----
    bfrag8 hb[4];
    {
      const unsigned short* hr = &sH1[(nt + cl) * 136 + q * 8];
#pragma unroll
      for (int ks = 0; ks < 4; ++ks) hb[ks] = *(const bfrag8*)(hr + ks * 32);
    }
    __syncthreads();   // h1 reads done -> overwrite sV as h2
#pragma unroll
    for (int rt = 0; rt < 4; ++rt) {
      f32x4 acc = {0.f, 0.f, 0.f, 0.f};
#pragma unroll
      for (int ks = 0; ks < 4; ++ks)
        acc = mfma16(*(const bfrag8*)&sW[8192 + ks * 2048 + (q * 64 + rt * 16 + cl) * 8], hb[ks], acc);
      const int c0 = rt * 16 + q * 4;
      uint2 hv = pk4(fmaxf(acc[0] + sB2[c0 + 0], 0.f),
                     fmaxf(acc[1] + sB2[c0 + 1], 0.f),
                     fmaxf(acc[2] + sB2[c0 + 2], 0.f),
                     fmaxf(acc[3] + sB2[c0 + 3], 0.f));
      *(uint2*)&sV[(nt + cl) * 72 + c0] = hv;   // reuse sV as h2
    }
    __syncthreads();

    // ---- GEMM3: K=64, no relu ----
    bfrag8 gb0 = *(const bfrag8*)&sV[(nt + cl) * 72 + q * 8];
    bfrag8 gb1 = *(const bfrag8*)&sV[(nt + cl) * 72 + 32 + q * 8];
    if (ng < NN) {
      float* outp = new_atoms + (size_t)ng * 32;
#pragma unroll
      for (int rt = 0; rt < 2; ++rt) {
        f32x4 acc = {0.f, 0.f, 0.f, 0.f};
        acc = mfma16(*(const bfrag8*)&sW[16384 + (q * 32 + rt * 16 + cl) * 8], gb0, acc);
        acc = mfma16(*(const bfrag8*)&sW[16384 + 1024 + (q * 32 + rt * 16 + cl) * 8], gb1, acc);
        const int c0 = rt * 16 + q * 4;
        float4 o;
        o.x = acc[0] + sB3[c0 + 0];
        o.y = acc[1] + sB3[c0 + 1];
        o.z = acc[2] + sB3[c0 + 2];
        o.w = acc[3] + sB3[c0 + 3];
        *(float4*)(outp + c0) = o;
      }
    }
  }
}

extern "C" void kernel_launch(void* const* d_in, const int* in_sizes, int n_in,
                              void* d_out, int out_size, void* d_ws, size_t ws_size,
                              hipStream_t stream) {
  const float* bonds = (const float*)d_in[0];
  const int* a1 = (const int*)d_in[1];
  const int* a2 = (const int*)d_in[2];
  const float* atoms = (const float*)d_in[3];
  const float* We1 = (const float*)d_in[4];
  const float* be1 = (const float*)d_in[5];
  const float* We2 = (const float*)d_in[6];
  const float* be2 = (const float*)d_in[7];
  const float* We3 = (const float*)d_in[8];
  const float* be3 = (const float*)d_in[9];
  const float* Wv1 = (const float*)d_in[10];
  const float* bv1 = (const float*)d_in[11];
  const float* Wv2 = (const float*)d_in[12];
  const float* bv2 = (const float*)d_in[13];
  const float* Wv3 = (const float*)d_in[14];
  const float* bv3 = (const float*)d_in[15];

  float* out = (float*)d_out;
  float* new_atoms = out;                       // [NN*32]; fallback: also mean_f32 scratch
  float* new_bonds = out + (size_t)NN * 32;     // [NE*32]

  char* ws = (char*)d_ws;
  int* cnt    = (int*)(ws + 0);                 // [NN], reused as fill cursor
  int* off    = (int*)(ws + 400000);            // [NN+1]
  int* bsum   = (int*)(ws + 800016);            // [512]
  unsigned short* wp = (unsigned short*)(ws + 802064);        // packed bf16 weights (81920 B)
  int* poscsr = (int*)(ws + 883984);            // [NE] pos (fast) or csr (fallback)
  unsigned short* atoms_bf = (unsigned short*)(ws + 7283984); // [NN*32] bf16 (6.4 MB)
  unsigned short* nb_bf    = (unsigned short*)(ws + 20083984); // [NE*32] bf16 (fast only)

  const int fast = (ws_size >= (size_t)122483984) ? 1 : 0;

  hipMemsetAsync(cnt, 0, (size_t)NN * 4, stream);

  prep<<<9535, 256, 0, stream>>>(atoms, atoms_bf, a2, cnt,
                                 We1, We2, We3, Wv1, Wv2, Wv3, wp);

  scan_blocks<<<NB_SCAN, 256, 0, stream>>>(cnt, off, bsum);
  scan_finalize<<<NB_SCAN, 256, 0, stream>>>(off, bsum, cnt);   // cursor := cnt
  fill_k<<<(NE + 255) / 256, 256, 0, stream>>>(a2, cnt, poscsr, fast);

  if (fast) {
    edge_kernel<1><<<EGRID, 256, 0, stream>>>(bonds, a1, a2, atoms_bf, be1, be2, be3, wp,
                                              new_bonds, poscsr, nb_bf);
    node_mlp<1><<<NGRID, 256, 0, stream>>>(atoms_bf, bv1, bv2, bv3, wp + 22528,
                                           off, nb_bf, nullptr, new_atoms);
  } else {
    edge_kernel<0><<<EGRID, 256, 0, stream>>>(bonds, a1, a2, atoms_bf, be1, be2, be3, wp,
                                              new_bonds, nullptr, nullptr);
    gather_rand<<<NN * 8 / 256, 256, 0, stream>>>(off, poscsr, new_bonds, new_atoms);
    node_mlp<0><<<NGRID, 256, 0, stream>>>(atoms_bf, bv1, bv2, bv3, wp + 22528,
                                           off, nullptr, new_atoms, new_atoms);
  }
}

// Round 14
// 392.764 us; speedup vs baseline: 1.1266x; 1.0172x over previous
//
#include <hip/hip_runtime.h>
#include <hip/hip_bf16.h>

#define NN 100000
#define NE 1600000
#define NB_SCAN 391   // ceil(NN/256)
#define ETILES 12500  // NE/128
#define EGRID 768
#define NGRID 1024

typedef __attribute__((ext_vector_type(8))) short bfrag8;   // 8 bf16 (4 VGPRs) MFMA operand
typedef __attribute__((ext_vector_type(4))) float f32x4;    // MFMA accumulator
typedef __attribute__((ext_vector_type(8))) unsigned short us8;
typedef __attribute__((ext_vector_type(4))) unsigned int u32x4;

__device__ __forceinline__ unsigned short f2bf(float f) {
  unsigned int u = __float_as_uint(f);
  u += 0x7fffu + ((u >> 16) & 1u);   // RNE
  return (unsigned short)(u >> 16);
}

// packed 2x f32 -> 2x bf16 in one u32 (no builtin on gfx950 -> inline asm, RNE)
__device__ __forceinline__ unsigned int pk2(float a, float b) {
  unsigned int r;
  asm("v_cvt_pk_bf16_f32 %0, %1, %2" : "=v"(r) : "v"(a), "v"(b));
  return r;
}

__device__ __forceinline__ uint2 pk4(float v0, float v1, float v2, float v3) {
  return make_uint2(pk2(v0, v1), pk2(v2, v3));
}

__device__ __forceinline__ bfrag8 pack8(float4 a, float4 b) {
  union { u32x4 u; bfrag8 f; } c;
  c.u[0] = pk2(a.x, a.y); c.u[1] = pk2(a.z, a.w);
  c.u[2] = pk2(b.x, b.y); c.u[3] = pk2(b.z, b.w);
  return c.f;
}

__device__ __forceinline__ bfrag8 as_frag(us8 v) {
  union { us8 u; bfrag8 f; } c;
  c.u = v;
  return c.f;
}

__device__ __forceinline__ bfrag8 as_frag_u(u32x4 v) {
  union { u32x4 u; bfrag8 f; } c;
  c.u = v;
  return c.f;
}

__device__ __forceinline__ unsigned int sh(unsigned int v, int src) {
  return (unsigned int)__shfl((int)v, src, 64);
}

__device__ __forceinline__ float bl(unsigned int u) { return __uint_as_float(u << 16); }
__device__ __forceinline__ float bh(unsigned int u) { return __uint_as_float(u & 0xffff0000u); }

__device__ __forceinline__ f32x4 mfma16(bfrag8 a, bfrag8 b, f32x4 c) {
  return __builtin_amdgcn_mfma_f32_16x16x32_bf16(a, b, c, 0, 0, 0);
}

__device__ __forceinline__ void gload_lds16(const void* g, void* l) {
  __builtin_amdgcn_global_load_lds(
      (const __attribute__((address_space(1))) unsigned int*)g,
      (__attribute__((address_space(3))) unsigned int*)l, 16, 0, 0);
}

// ---------------- prep: cvt_atoms + count + pack_w in ONE launch ----------------
__global__ void prep(const float* __restrict__ atoms, unsigned short* __restrict__ atoms_bf,
                     const int* __restrict__ a2, int* __restrict__ cnt,
                     const float* __restrict__ We1, const float* __restrict__ We2,
                     const float* __restrict__ We3, const float* __restrict__ Wv1,
                     const float* __restrict__ Wv2, const float* __restrict__ Wv3,
                     unsigned short* __restrict__ wp) {
  const int b = blockIdx.x, tid = threadIdx.x;
  if (b < 3125) {                       // cvt_atoms: NN*32/4 = 800000 float4
    const int i = b * 256 + tid;
    float4 v = *(const float4*)(atoms + (size_t)i * 4);
    *(uint2*)(atoms_bf + (size_t)i * 4) = pk4(v.x, v.y, v.z, v.w);
  } else if (b < 3125 + 6250) {         // count
    const int e = (b - 3125) * 256 + tid;
    if (e < NE) atomicAdd(&cnt[a2[e]], 1);
  } else {                              // pack_w over flat table (40960 elems)
    const int i = (b - 9375) * 256 + tid;
    const float* src; int base, N;
    if (i < 12288)      { src = We1; base = 0;     N = 128; }
    else if (i < 20480) { src = We2; base = 12288; N = 64;  }
    else if (i < 22528) { src = We3; base = 20480; N = 32;  }
    else if (i < 30720) { src = Wv1; base = 22528; N = 128; }
    else if (i < 38912) { src = Wv2; base = 30720; N = 64;  }
    else                { src = Wv3; base = 38912; N = 32;  }
    const int il = i - base;
    const int j = il & 7, gc = il >> 3;
    const int c = gc % N, g = gc / N;
    wp[i] = f2bf(src[(g * 8 + j) * N + c]);
  }
}

// ---------------- CSR construction ----------------
__global__ void scan_blocks(const int* __restrict__ cnt, int* __restrict__ off,
                            int* __restrict__ bsum) {
  __shared__ int s[256];
  const int t = threadIdx.x;
  const int idx = blockIdx.x * 256 + t;
  int v = (idx < NN) ? cnt[idx] : 0;
  s[t] = v;
  __syncthreads();
  for (int d = 1; d < 256; d <<= 1) {
    int x = (t >= d) ? s[t - d] : 0;
    __syncthreads();
    s[t] += x;
    __syncthreads();
  }
  if (idx < NN) off[idx] = s[t] - v;          // exclusive within block
  if (t == 255) bsum[blockIdx.x] = s[255];
}

// finalize: each block computes its own base = sum(bsum[0..b-1])
__global__ void scan_finalize(int* __restrict__ off, const int* __restrict__ bsum,
                              int* __restrict__ cursor) {
  __shared__ int red[256];
  const int b = blockIdx.x, t = threadIdx.x;
  int s = 0;
  for (int k = t; k < b; k += 256) s += bsum[k];
  red[t] = s;
  __syncthreads();
  for (int d = 128; d > 0; d >>= 1) {
    if (t < d) red[t] += red[t + d];
    __syncthreads();
  }
  const int base = red[0];
  const int idx = b * 256 + t;
  if (idx < NN) {
    int o = off[idx] + base;
    off[idx] = o;
    cursor[idx] = o;
  }
  if (idx == 0) off[NN] = NE;
}

// mode 1: pos[e] = slot (coalesced write); mode 0: csr[slot] = e (scattered)
__global__ void fill_k(const int* __restrict__ a2, int* __restrict__ cursor,
                       int* __restrict__ buf, int mode) {
  int e = blockIdx.x * 256 + threadIdx.x;
  if (e < NE) {
    int p = atomicAdd(&cursor[a2[e]], 1);
    if (mode) buf[e] = p;
    else buf[p] = e;
  }
}

// ---------------- Edge kernel: persistent, shuffle datapath + LDS out-stage ----
// Redistribution law (verified R12): dest lane (cl,q) word w comes from
// lane cl + ((q&1)*2 + (w>>1))*16, register rt_src = 2*ks + (q>>1), pair w&1.
template <int FAST>
__global__ __launch_bounds__(256, 3) void edge_kernel(
    const float* __restrict__ bonds, const int* __restrict__ a1p, const int* __restrict__ a2p,
    const unsigned short* __restrict__ atoms_bf,
    const float* __restrict__ be1, const float* __restrict__ be2, const float* __restrict__ be3,
    const unsigned short* __restrict__ wpack,
    float* __restrict__ new_bonds,
    const int* __restrict__ pos, unsigned short* __restrict__ nb_bf) {
  __shared__ unsigned short sW[20480];          // We1p[12288] We2p[8192] = 40960 B
  __shared__ float sB1[128], sB2[64], sB3[32];
  __shared__ unsigned short sOut[128 * 40];     // bf16 out-stage (10240 B); total ~52.1 KB

  const int tid = threadIdx.x;
  const int lane = tid & 63, wv = tid >> 6;
  const int cl = lane & 15, q = lane >> 4;
  const int esub = wv * 32 + cl;                // + t*16
  const int srcA = cl + ((q & 1) << 5);
  const int srcB = srcA + 16;
  const bool hi = (lane & 32) != 0;             // q >= 2

  // ---- stage We1p+We2p (async DMA, 40 KiB) + biases; We3 frags -> registers
  {
    const char* src = (const char*)wpack;
    char* dst = (char*)sW;
#pragma unroll
    for (int i = 0; i < 10; ++i) {
      const int c = i * 4 + wv;
      gload_lds16(src + c * 1024 + lane * 16, dst + c * 1024);
    }
  }
  bfrag8 w3[2][2];
#pragma unroll
  for (int ks = 0; ks < 2; ++ks)
#pragma unroll
    for (int rt = 0; rt < 2; ++rt)
      w3[ks][rt] = *(const bfrag8*)(wpack + 20480 + ks * 1024 + (q * 32 + rt * 16 + cl) * 8);
  if (tid < 128) sB1[tid] = be1[tid];
  else if (tid < 192) sB2[tid - 128] = be2[tid - 128];
  else if (tid < 224) sB3[tid - 192] = be3[tid - 192];

  int tile = blockIdx.x;
  us8 ra1[2], ra2[2];      // atom bf16 frags (raw)
  float4 rb[2][2];         // bond f32 raw
  int ia1n[2], ia2n[2];    // indices for NEXT tile
  int slotc = 0;           // CSR slot for this thread's row (tid<128)

  // ---- prologue: gather tile0; indices for tile0+G
#pragma unroll
  for (int t = 0; t < 2; ++t) {
    const int e = tile * 128 + esub + t * 16;
    const int ia1 = a1p[e], ia2 = a2p[e];
    ra1[t] = *(const us8*)(atoms_bf + (size_t)ia1 * 32 + q * 8);
    ra2[t] = *(const us8*)(atoms_bf + (size_t)ia2 * 32 + q * 8);
    const float* bp = bonds + (size_t)e * 32 + q * 8;
    rb[t][0] = *(const float4*)(bp);
    rb[t][1] = *(const float4*)(bp + 4);
  }
  if (FAST && tid < 128) slotc = pos[tile * 128 + tid];
  {
    int tn = tile + EGRID; if (tn >= ETILES) tn = tile;
#pragma unroll
    for (int t = 0; t < 2; ++t) {
      const int e = tn * 128 + esub + t * 16;
      ia1n[t] = a1p[e]; ia2n[t] = a2p[e];
    }
  }
  __syncthreads();   // weights + biases staged

  for (; tile < ETILES; tile += EGRID) {
    // ---- convert current frags (frees ra/rb)
    bfrag8 xb0[2], xb1[2], xb2[2];
#pragma unroll
    for (int t = 0; t < 2; ++t) {
      xb0[t] = as_frag(ra1[t]);
      xb1[t] = as_frag(ra2[t]);
      xb2[t] = pack8(rb[t][0], rb[t][1]);
    }
    // ---- issue next tile's gathers, then next-next indices
    const int tn = (tile + EGRID < ETILES) ? tile + EGRID : tile;
#pragma unroll
    for (int t = 0; t < 2; ++t) {
      ra1[t] = *(const us8*)(atoms_bf + (size_t)ia1n[t] * 32 + q * 8);
      ra2[t] = *(const us8*)(atoms_bf + (size_t)ia2n[t] * 32 + q * 8);
      const int e = tn * 128 + esub + t * 16;
      const float* bp = bonds + (size_t)e * 32 + q * 8;
      rb[t][0] = *(const float4*)(bp);
      rb[t][1] = *(const float4*)(bp + 4);
    }
    int slotn = 0;
    if (FAST && tid < 128) slotn = pos[tn * 128 + tid];
    {
      int tnn = tile + 2 * EGRID; if (tnn >= ETILES) tnn = tn;
#pragma unroll
      for (int t = 0; t < 2; ++t) {
        const int e = tnn * 128 + esub + t * 16;
        ia1n[t] = a1p[e]; ia2n[t] = a2p[e];
      }
    }

    // ---- GEMM1: h1 into hp[t][rt][pair] (in-register) ----
    unsigned int hp[2][8][2];
#pragma unroll
    for (int rt = 0; rt < 8; ++rt) {
      const unsigned short* wa = &sW[(q * 128 + rt * 16 + cl) * 8];
      bfrag8 w0 = *(const bfrag8*)(wa);
      bfrag8 w1 = *(const bfrag8*)(wa + 4096);
      bfrag8 w2 = *(const bfrag8*)(wa + 8192);
      const int c0 = rt * 16 + q * 4;
#pragma unroll
      for (int t = 0; t < 2; ++t) {
        f32x4 acc = {0.f, 0.f, 0.f, 0.f};
        acc = mfma16(w0, xb0[t], acc);
        acc = mfma16(w1, xb1[t], acc);
        acc = mfma16(w2, xb2[t], acc);
        hp[t][rt][0] = pk2(fmaxf(acc[0] + sB1[c0 + 0], 0.f),
                           fmaxf(acc[1] + sB1[c0 + 1], 0.f));
        hp[t][rt][1] = pk2(fmaxf(acc[2] + sB1[c0 + 2], 0.f),
                           fmaxf(acc[3] + sB1[c0 + 3], 0.f));
      }
    }

    // ---- GEMM2: K=128, B-frags via shuffle redistribution ----
    f32x4 acc2[2][4];
#pragma unroll
    for (int t = 0; t < 2; ++t)
#pragma unroll
      for (int rt = 0; rt < 4; ++rt) acc2[t][rt] = (f32x4){0.f, 0.f, 0.f, 0.f};
#pragma unroll
    for (int ks = 0; ks < 4; ++ks) {
      bfrag8 hb[2];
#pragma unroll
      for (int t = 0; t < 2; ++t) {
        u32x4 bw;
        unsigned int x, y;
        x = sh(hp[t][2 * ks][0], srcA); y = sh(hp[t][2 * ks + 1][0], srcA); bw[0] = hi ? y : x;
        x = sh(hp[t][2 * ks][1], srcA); y = sh(hp[t][2 * ks + 1][1], srcA); bw[1] = hi ? y : x;
        x = sh(hp[t][2 * ks][0], srcB); y = sh(hp[t][2 * ks + 1][0], srcB); bw[2] = hi ? y : x;
        x = sh(hp[t][2 * ks][1], srcB); y = sh(hp[t][2 * ks + 1][1], srcB); bw[3] = hi ? y : x;
        hb[t] = as_frag_u(bw);
      }
#pragma unroll
      for (int rt = 0; rt < 4; ++rt) {
        bfrag8 w = *(const bfrag8*)&sW[12288 + ks * 2048 + (q * 64 + rt * 16 + cl) * 8];
#pragma unroll
        for (int t = 0; t < 2; ++t) acc2[t][rt] = mfma16(w, hb[t], acc2[t][rt]);
      }
    }
    unsigned int hp2[2][4][2];
#pragma unroll
    for (int rt = 0; rt < 4; ++rt) {
      const int c0 = rt * 16 + q * 4;
#pragma unroll
      for (int t = 0; t < 2; ++t) {
        hp2[t][rt][0] = pk2(fmaxf(acc2[t][rt][0] + sB2[c0 + 0], 0.f),
                            fmaxf(acc2[t][rt][1] + sB2[c0 + 1], 0.f));
        hp2[t][rt][1] = pk2(fmaxf(acc2[t][rt][2] + sB2[c0 + 2], 0.f),
                            fmaxf(acc2[t][rt][3] + sB2[c0 + 3], 0.f));
      }
    }

    // ---- GEMM3: K=64, weights in registers ----
    f32x4 acc3[2][2];
#pragma unroll
    for (int t = 0; t < 2; ++t)
#pragma unroll
      for (int rt = 0; rt < 2; ++rt) acc3[t][rt] = (f32x4){0.f, 0.f, 0.f, 0.f};
#pragma unroll
    for (int ks = 0; ks < 2; ++ks) {
      bfrag8 gb[2];
#pragma unroll
      for (int t = 0; t < 2; ++t) {
        u32x4 bw;
        unsigned int x, y;
        x = sh(hp2[t][2 * ks][0], srcA); y = sh(hp2[t][2 * ks + 1][0], srcA); bw[0] = hi ? y : x;
        x = sh(hp2[t][2 * ks][1], srcA); y = sh(hp2[t][2 * ks + 1][1], srcA); bw[1] = hi ? y : x;
        x = sh(hp2[t][2 * ks][0], srcB); y = sh(hp2[t][2 * ks + 1][0], srcB); bw[2] = hi ? y : x;
        x = sh(hp2[t][2 * ks][1], srcB); y = sh(hp2[t][2 * ks + 1][1], srcB); bw[3] = hi ? y : x;
        gb[t] = as_frag_u(bw);
      }
#pragma unroll
      for (int rt = 0; rt < 2; ++rt)
#pragma unroll
        for (int t = 0; t < 2; ++t) acc3[t][rt] = mfma16(w3[ks][rt], gb[t], acc3[t][rt]);
    }

    // ---- epilogue: f32 store + (FAST) bf16 out-stage -> 64B row scatter ----
#pragma unroll
    for (int rt = 0; rt < 2; ++rt) {
      const int c0 = rt * 16 + q * 4;
#pragma unroll
      for (int t = 0; t < 2; ++t) {
        float4 o;
        o.x = acc3[t][rt][0] + sB3[c0 + 0];
        o.y = acc3[t][rt][1] + sB3[c0 + 1];
        o.z = acc3[t][rt][2] + sB3[c0 + 2];
        o.w = acc3[t][rt][3] + sB3[c0 + 3];
        const int e = tile * 128 + esub + t * 16;
        *(float4*)(new_bonds + (size_t)e * 32 + c0) = o;
        if (FAST) {
          *(uint2*)&sOut[(esub + t * 16) * 40 + c0] =
              make_uint2(pk2(o.x, o.y), pk2(o.z, o.w));
        }
      }
    }
    if (FAST) {
      __syncthreads();   // out-stage complete (rows span waves)
      if (tid < 128) {
        const u32x4* src = (const u32x4*)&sOut[tid * 40];
        u32x4* dst = (u32x4*)(nb_bf + (size_t)slotc * 32);
#pragma unroll
        for (int k = 0; k < 4; ++k) dst[k] = src[k];   // 64B contiguous per thread
      }
      slotc = slotn;
      __syncthreads();   // scatter reads done -> next tile may overwrite sOut
    }
  }
}

// ---------------- Gather (fast): sequential segmented mean over CSR-ordered bf16 rows ----
__global__ __launch_bounds__(256, 8) void gather_seq(
    const int* __restrict__ off, const unsigned short* __restrict__ nb_bf,
    unsigned short* __restrict__ mean_bf) {
  const int gt = blockIdx.x * 256 + threadIdx.x;   // NN*8
  const int n = gt >> 3, sl = gt & 7;              // 8 B slice (4 bf16) per thread
  const int o0 = off[n], o1 = off[n + 1];
  const int deg = o1 - o0;
  float s0 = 0.f, s1 = 0.f, s2 = 0.f, s3 = 0.f;
  const unsigned short* p = nb_bf + (size_t)o0 * 32 + sl * 4;
  int i = 0;
  for (; i + 1 < deg; i += 2) {
    uint2 a = *(const uint2*)(p);
    uint2 b = *(const uint2*)(p + 32);
    p += 64;
    s0 += bl(a.x) + bl(b.x); s1 += bh(a.x) + bh(b.x);
    s2 += bl(a.y) + bl(b.y); s3 += bh(a.y) + bh(b.y);
  }
  if (i < deg) {
    uint2 a = *(const uint2*)(p);
    s0 += bl(a.x); s1 += bh(a.x); s2 += bl(a.y); s3 += bh(a.y);
  }
  const float inv = 1.0f / fmaxf((float)deg, 1.0f);
  *(uint2*)(mean_bf + (size_t)n * 32 + sl * 4) =
      make_uint2(pk2(s0 * inv, s1 * inv), pk2(s2 * inv, s3 * inv));
}

// ---------------- Gather (fallback): random rows via csr ----------------
__global__ __launch_bounds__(256, 8) void gather_rand(
    const int* __restrict__ off, const int* __restrict__ csr,
    const float* __restrict__ new_bonds, float* __restrict__ mean_f32) {
  const int tid = blockIdx.x * 256 + threadIdx.x;   // NN*8
  const int n = tid >> 3, sl = tid & 7;             // 16 B slice per thread
  const int o0 = off[n], o1 = off[n + 1];
  float4 s0 = {0.f, 0.f, 0.f, 0.f}, s1 = {0.f, 0.f, 0.f, 0.f};
  int i = o0;
  for (; i + 1 < o1; i += 2) {
    const int ea = csr[i], eb = csr[i + 1];
    float4 a = *(const float4*)(new_bonds + (size_t)ea * 32 + sl * 4);
    float4 b = *(const float4*)(new_bonds + (size_t)eb * 32 + sl * 4);
    s0.x += a.x; s0.y += a.y; s0.z += a.z; s0.w += a.w;
    s1.x += b.x; s1.y += b.y; s1.z += b.z; s1.w += b.w;
  }
  if (i < o1) {
    const int ea = csr[i];
    float4 a = *(const float4*)(new_bonds + (size_t)ea * 32 + sl * 4);
    s0.x += a.x; s0.y += a.y; s0.z += a.z; s0.w += a.w;
  }
  const float inv = 1.0f / fmaxf((float)(o1 - o0), 1.0f);
  float4 m;
  m.x = (s0.x + s1.x) * inv;
  m.y = (s0.y + s1.y) * inv;
  m.z = (s0.z + s1.z) * inv;
  m.w = (s0.w + s1.w) * inv;
  *(float4*)(mean_f32 + (size_t)n * 32 + sl * 4) = m;
}

// ---------------- Node MLP: persistent, 64 nodes/tile, streaming inputs -------
// MODE 1: mean_src = bf16[NN*32]; MODE 0: mean_src = f32[NN*32]
template <int MODE>
__global__ __launch_bounds__(256, 4) void node_mlp(
    const unsigned short* __restrict__ atoms_bf,
    const float* __restrict__ bv1, const float* __restrict__ bv2, const float* __restrict__ bv3,
    const unsigned short* __restrict__ wpack,
    const void* __restrict__ mean_src, float* __restrict__ new_atoms) {
  __shared__ unsigned short sW[18432];          // Wv1p[8192] Wv2p[8192] Wv3p[2048]
  __shared__ float sB1[128], sB2[64], sB3[32];
  __shared__ unsigned short sV[64 * 72];        // v_in [64][64] pad->72; reused as h2
  __shared__ unsigned short sH1[64 * 136];

  const int tid = threadIdx.x;
  const int lane = tid & 63, wv = tid >> 6;
  const int cl = lane & 15, q = lane >> 4;
  const int nl = tid >> 2, l4 = tid & 3;

  {
    const uint4* src = (const uint4*)wpack;
    uint4* dst = (uint4*)sW;
#pragma unroll
    for (int i = 0; i < 9; ++i) dst[tid + i * 256] = src[tid + i * 256];
  }
  if (tid < 128) sB1[tid] = bv1[tid];
  if (tid < 64) sB2[tid] = bv2[tid];
  if (tid < 32) sB3[tid] = bv3[tid];

  for (int n0 = blockIdx.x * 64; n0 < NN; n0 += NGRID * 64) {
    __syncthreads();   // weights staged / previous tile's LDS reads complete

    // stage v tile: cols [0,32) = mean, [32,64) = atoms (bf16 copy)
    {
      const int n = n0 + nl;
      if (n < NN) {
        if (l4 < 2) {
          if (MODE == 1) {
            const unsigned short* mp = (const unsigned short*)mean_src + (size_t)n * 32 + l4 * 16;
            *(us8*)&sV[nl * 72 + l4 * 16] = *(const us8*)(mp);
            *(us8*)&sV[nl * 72 + l4 * 16 + 8] = *(const us8*)(mp + 8);
          } else {
            const float* sp = (const float*)mean_src + (size_t)n * 32 + l4 * 16;
            float4 a = *(const float4*)(sp);
            float4 b = *(const float4*)(sp + 4);
            float4 c = *(const float4*)(sp + 8);
            float4 d = *(const float4*)(sp + 12);
            uint4 o0, o1;
            o0.x = pk2(a.x, a.y); o0.y = pk2(a.z, a.w);
            o0.z = pk2(b.x, b.y); o0.w = pk2(b.z, b.w);
            o1.x = pk2(c.x, c.y); o1.y = pk2(c.z, c.w);
            o1.z = pk2(d.x, d.y); o1.w = pk2(d.z, d.w);
            *(uint4*)&sV[nl * 72 + l4 * 16] = o0;
            *(uint4*)&sV[nl * 72 + l4 * 16 + 8] = o1;
          }
        } else {
          const unsigned short* ap = atoms_bf + (size_t)n * 32 + (l4 - 2) * 16;
          *(us8*)&sV[nl * 72 + 32 + (l4 - 2) * 16] = *(const us8*)(ap);
          *(us8*)&sV[nl * 72 + 32 + (l4 - 2) * 16 + 8] = *(const us8*)(ap + 8);
        }
      } else {
        us8 z = {0, 0, 0, 0, 0, 0, 0, 0};
        *(us8*)&sV[nl * 72 + l4 * 16] = z;
        *(us8*)&sV[nl * 72 + l4 * 16 + 8] = z;
      }
    }
    __syncthreads();

    const int nt = wv * 16;
    const int ng = n0 + nt + cl;

    // ---- GEMM1: K=64 ----
    bfrag8 vb0 = *(const bfrag8*)&sV[(nt + cl) * 72 + q * 8];
    bfrag8 vb1 = *(const bfrag8*)&sV[(nt + cl) * 72 + 32 + q * 8];
#pragma unroll
    for (int rt = 0; rt < 8; ++rt) {
      f32x4 acc = {0.f, 0.f, 0.f, 0.f};
      acc = mfma16(*(const bfrag8*)&sW[(q * 128 + rt * 16 + cl) * 8], vb0, acc);
      acc = mfma16(*(const bfrag8*)&sW[4096 + (q * 128 + rt * 16 + cl) * 8], vb1, acc);
      const int c0 = rt * 16 + q * 4;
      uint2 hv = pk4(fmaxf(acc[0] + sB1[c0 + 0], 0.f),
                     fmaxf(acc[1] + sB1[c0 + 1], 0.f),
                     fmaxf(acc[2] + sB1[c0 + 2], 0.f),
                     fmaxf(acc[3] + sB1[c0 + 3], 0.f));
      *(uint2*)&sH1[(nt + cl) * 136 + c0] = hv;
    }
    __syncthreads();

    // ---- GEMM2: K=128 ----
    bfrag8 hb[4];
    {
      const unsigned short* hr = &sH1[(nt + cl) * 136 + q * 8];
#pragma unroll
      for (int ks = 0; ks < 4; ++ks) hb[ks] = *(const bfrag8*)(hr + ks * 32);
    }
    __syncthreads();   // h1 reads done -> overwrite sV as h2
#pragma unroll
    for (int rt = 0; rt < 4; ++rt) {
      f32x4 acc = {0.f, 0.f, 0.f, 0.f};
#pragma unroll
      for (int ks = 0; ks < 4; ++ks)
        acc = mfma16(*(const bfrag8*)&sW[8192 + ks * 2048 + (q * 64 + rt * 16 + cl) * 8], hb[ks], acc);
      const int c0 = rt * 16 + q * 4;
      uint2 hv = pk4(fmaxf(acc[0] + sB2[c0 + 0], 0.f),
                     fmaxf(acc[1] + sB2[c0 + 1], 0.f),
                     fmaxf(acc[2] + sB2[c0 + 2], 0.f),
                     fmaxf(acc[3] + sB2[c0 + 3], 0.f));
      *(uint2*)&sV[(nt + cl) * 72 + c0] = hv;   // reuse sV as h2
    }
    __syncthreads();

    // ---- GEMM3: K=64, no relu ----
    bfrag8 gb0 = *(const bfrag8*)&sV[(nt + cl) * 72 + q * 8];
    bfrag8 gb1 = *(const bfrag8*)&sV[(nt + cl) * 72 + 32 + q * 8];
    if (ng < NN) {
      float* outp = new_atoms + (size_t)ng * 32;
#pragma unroll
      for (int rt = 0; rt < 2; ++rt) {
        f32x4 acc = {0.f, 0.f, 0.f, 0.f};
        acc = mfma16(*(const bfrag8*)&sW[16384 + (q * 32 + rt * 16 + cl) * 8], gb0, acc);
        acc = mfma16(*(const bfrag8*)&sW[16384 + 1024 + (q * 32 + rt * 16 + cl) * 8], gb1, acc);
        const int c0 = rt * 16 + q * 4;
        float4 o;
        o.x = acc[0] + sB3[c0 + 0];
        o.y = acc[1] + sB3[c0 + 1];
        o.z = acc[2] + sB3[c0 + 2];
        o.w = acc[3] + sB3[c0 + 3];
        *(float4*)(outp + c0) = o;
      }
    }
  }
}

extern "C" void kernel_launch(void* const* d_in, const int* in_sizes, int n_in,
                              void* d_out, int out_size, void* d_ws, size_t ws_size,
                              hipStream_t stream) {
  const float* bonds = (const float*)d_in[0];
  const int* a1 = (const int*)d_in[1];
  const int* a2 = (const int*)d_in[2];
  const float* atoms = (const float*)d_in[3];
  const float* We1 = (const float*)d_in[4];
  const float* be1 = (const float*)d_in[5];
  const float* We2 = (const float*)d_in[6];
  const float* be2 = (const float*)d_in[7];
  const float* We3 = (const float*)d_in[8];
  const float* be3 = (const float*)d_in[9];
  const float* Wv1 = (const float*)d_in[10];
  const float* bv1 = (const float*)d_in[11];
  const float* Wv2 = (const float*)d_in[12];
  const float* bv2 = (const float*)d_in[13];
  const float* Wv3 = (const float*)d_in[14];
  const float* bv3 = (const float*)d_in[15];

  float* out = (float*)d_out;
  float* new_atoms = out;                       // [NN*32]; fallback: also mean_f32 scratch
  float* new_bonds = out + (size_t)NN * 32;     // [NE*32]

  char* ws = (char*)d_ws;
  int* cnt    = (int*)(ws + 0);                 // [NN], reused as fill cursor
  int* off    = (int*)(ws + 400000);            // [NN+1]
  int* bsum   = (int*)(ws + 800016);            // [512]
  unsigned short* wp = (unsigned short*)(ws + 802064);        // packed bf16 weights (81920 B)
  int* poscsr = (int*)(ws + 883984);            // [NE] pos (fast) or csr (fallback)
  unsigned short* atoms_bf = (unsigned short*)(ws + 7283984); // [NN*32] bf16 (6.4 MB)
  unsigned short* mean_bf  = (unsigned short*)(ws + 13683984); // [NN*32] bf16 (fast only)
  unsigned short* nb_bf    = (unsigned short*)(ws + 20083984); // [NE*32] bf16 (fast only)

  const int fast = (ws_size >= (size_t)122483984) ? 1 : 0;

  hipMemsetAsync(cnt, 0, (size_t)NN * 4, stream);

  prep<<<9535, 256, 0, stream>>>(atoms, atoms_bf, a2, cnt,
                                 We1, We2, We3, Wv1, Wv2, Wv3, wp);

  scan_blocks<<<NB_SCAN, 256, 0, stream>>>(cnt, off, bsum);
  scan_finalize<<<NB_SCAN, 256, 0, stream>>>(off, bsum, cnt);   // cursor := cnt
  fill_k<<<(NE + 255) / 256, 256, 0, stream>>>(a2, cnt, poscsr, fast);

  if (fast) {
    edge_kernel<1><<<EGRID, 256, 0, stream>>>(bonds, a1, a2, atoms_bf, be1, be2, be3, wp,
                                              new_bonds, poscsr, nb_bf);
    gather_seq<<<NN * 8 / 256, 256, 0, stream>>>(off, nb_bf, mean_bf);
    node_mlp<1><<<NGRID, 256, 0, stream>>>(atoms_bf, bv1, bv2, bv3, wp + 22528,
                                           mean_bf, new_atoms);
  } else {
    edge_kernel<0><<<EGRID, 256, 0, stream>>>(bonds, a1, a2, atoms_bf, be1, be2, be3, wp,
                                              new_bonds, nullptr, nullptr);
    gather_rand<<<NN * 8 / 256, 256, 0, stream>>>(off, poscsr, new_bonds, new_atoms);
    node_mlp<0><<<NGRID, 256, 0, stream>>>(atoms_bf, bv1, bv2, bv3, wp + 22528,
                                           new_atoms, new_atoms);
  }
}

// Round 15
// 382.482 us; speedup vs baseline: 1.1569x; 1.0269x over previous
//
#include <hip/hip_runtime.h>
#include <hip/hip_bf16.h>

#define NN 100000
#define NE 1600000
#define NB_SCAN 391   // ceil(NN/256)
#define ETILES 12500  // NE/128
#define EGRID 512
#define NGRID 1024

typedef __attribute__((ext_vector_type(8))) short bfrag8;   // 8 bf16 (4 VGPRs) MFMA operand
typedef __attribute__((ext_vector_type(4))) float f32x4;    // MFMA accumulator
typedef __attribute__((ext_vector_type(8))) unsigned short us8;
typedef __attribute__((ext_vector_type(4))) unsigned int u32x4;

__device__ __forceinline__ unsigned short f2bf(float f) {
  unsigned int u = __float_as_uint(f);
  u += 0x7fffu + ((u >> 16) & 1u);   // RNE
  return (unsigned short)(u >> 16);
}

// packed 2x f32 -> 2x bf16 in one u32 (no builtin on gfx950 -> inline asm, RNE)
__device__ __forceinline__ unsigned int pk2(float a, float b) {
  unsigned int r;
  asm("v_cvt_pk_bf16_f32 %0, %1, %2" : "=v"(r) : "v"(a), "v"(b));
  return r;
}

__device__ __forceinline__ uint2 pk4(float v0, float v1, float v2, float v3) {
  return make_uint2(pk2(v0, v1), pk2(v2, v3));
}

__device__ __forceinline__ bfrag8 pack8(float4 a, float4 b) {
  union { u32x4 u; bfrag8 f; } c;
  c.u[0] = pk2(a.x, a.y); c.u[1] = pk2(a.z, a.w);
  c.u[2] = pk2(b.x, b.y); c.u[3] = pk2(b.z, b.w);
  return c.f;
}

__device__ __forceinline__ bfrag8 as_frag(us8 v) {
  union { us8 u; bfrag8 f; } c;
  c.u = v;
  return c.f;
}

__device__ __forceinline__ float bl(unsigned int u) { return __uint_as_float(u << 16); }
__device__ __forceinline__ float bh(unsigned int u) { return __uint_as_float(u & 0xffff0000u); }

__device__ __forceinline__ f32x4 mfma16(bfrag8 a, bfrag8 b, f32x4 c) {
  return __builtin_amdgcn_mfma_f32_16x16x32_bf16(a, b, c, 0, 0, 0);
}

__device__ __forceinline__ void gload_lds16(const void* g, void* l) {
  __builtin_amdgcn_global_load_lds(
      (const __attribute__((address_space(1))) unsigned int*)g,
      (__attribute__((address_space(3))) unsigned int*)l, 16, 0, 0);
}

// ---------------- prep: cvt_atoms + count + pack_w in ONE launch ----------------
__global__ void prep(const float* __restrict__ atoms, unsigned short* __restrict__ atoms_bf,
                     const int* __restrict__ a2, int* __restrict__ cnt,
                     const float* __restrict__ We1, const float* __restrict__ We2,
                     const float* __restrict__ We3, const float* __restrict__ Wv1,
                     const float* __restrict__ Wv2, const float* __restrict__ Wv3,
                     unsigned short* __restrict__ wp) {
  const int b = blockIdx.x, tid = threadIdx.x;
  if (b < 3125) {                       // cvt_atoms: NN*32/4 = 800000 float4
    const int i = b * 256 + tid;
    float4 v = *(const float4*)(atoms + (size_t)i * 4);
    *(uint2*)(atoms_bf + (size_t)i * 4) = pk4(v.x, v.y, v.z, v.w);
  } else if (b < 3125 + 6250) {         // count
    const int e = (b - 3125) * 256 + tid;
    if (e < NE) atomicAdd(&cnt[a2[e]], 1);
  } else {                              // pack_w over flat table (40960 elems)
    const int i = (b - 9375) * 256 + tid;
    const float* src; int base, N;
    if (i < 12288)      { src = We1; base = 0;     N = 128; }
    else if (i < 20480) { src = We2; base = 12288; N = 64;  }
    else if (i < 22528) { src = We3; base = 20480; N = 32;  }
    else if (i < 30720) { src = Wv1; base = 22528; N = 128; }
    else if (i < 38912) { src = Wv2; base = 30720; N = 64;  }
    else                { src = Wv3; base = 38912; N = 32;  }
    const int il = i - base;
    const int j = il & 7, gc = il >> 3;
    const int c = gc % N, g = gc / N;
    wp[i] = f2bf(src[(g * 8 + j) * N + c]);
  }
}

// ---------------- CSR construction ----------------
__global__ void scan_blocks(const int* __restrict__ cnt, int* __restrict__ off,
                            int* __restrict__ bsum) {
  __shared__ int s[256];
  const int t = threadIdx.x;
  const int idx = blockIdx.x * 256 + t;
  int v = (idx < NN) ? cnt[idx] : 0;
  s[t] = v;
  __syncthreads();
  for (int d = 1; d < 256; d <<= 1) {
    int x = (t >= d) ? s[t - d] : 0;
    __syncthreads();
    s[t] += x;
    __syncthreads();
  }
  if (idx < NN) off[idx] = s[t] - v;          // exclusive within block
  if (t == 255) bsum[blockIdx.x] = s[255];
}

// finalize: each block computes its own base = sum(bsum[0..b-1])
__global__ void scan_finalize(int* __restrict__ off, const int* __restrict__ bsum,
                              int* __restrict__ cursor) {
  __shared__ int red[256];
  const int b = blockIdx.x, t = threadIdx.x;
  int s = 0;
  for (int k = t; k < b; k += 256) s += bsum[k];
  red[t] = s;
  __syncthreads();
  for (int d = 128; d > 0; d >>= 1) {
    if (t < d) red[t] += red[t + d];
    __syncthreads();
  }
  const int base = red[0];
  const int idx = b * 256 + t;
  if (idx < NN) {
    int o = off[idx] + base;
    off[idx] = o;
    cursor[idx] = o;
  }
  if (idx == 0) off[NN] = NE;
}

// mode 1: pos[e] = slot (coalesced write); mode 0: csr[slot] = e (scattered)
__global__ void fill_k(const int* __restrict__ a2, int* __restrict__ cursor,
                       int* __restrict__ buf, int mode) {
  int e = blockIdx.x * 256 + threadIdx.x;
  if (e < NE) {
    int p = atomicAdd(&cursor[a2[e]], 1);
    if (mode) buf[e] = p;
    else buf[p] = e;
  }
}

// ---------------- Edge kernel: persistent, 128 edges/tile, 1-tile pipeline ----------------
// FAST=1: also emit bf16 rows to nb_bf[pos[e]] via LDS restage + 64B-contiguous row writes.
template <int FAST>
__global__ __launch_bounds__(256, 2) void edge_kernel(
    const float* __restrict__ bonds, const int* __restrict__ a1p, const int* __restrict__ a2p,
    const unsigned short* __restrict__ atoms_bf,
    const float* __restrict__ be1, const float* __restrict__ be2, const float* __restrict__ be3,
    const unsigned short* __restrict__ wpack,
    float* __restrict__ new_bonds,
    const int* __restrict__ pos, unsigned short* __restrict__ nb_bf) {
  __shared__ unsigned short sW[22528];          // We1p[12288] We2p[8192] We3p[2048] = 45056 B
  __shared__ float sB1[128], sB2[64], sB3[32];
  __shared__ unsigned short sH1[128 * 136];     // h1 [128][128] pad->136; aliased: h2 [128][72] in
                                                // [0,9216); out-stage [128][40] in [9216,14336)

  const int tid = threadIdx.x;
  const int lane = tid & 63, wv = tid >> 6;
  const int cl = lane & 15, q = lane >> 4;
  const int esub = wv * 32 + cl;                // + t*16

  // ---- stage weights ONCE (async DMA) + biases
  {
    const char* src = (const char*)wpack;
    char* dst = (char*)sW;
#pragma unroll
    for (int i = 0; i < 11; ++i) {
      const int c = i * 4 + wv;
      gload_lds16(src + c * 1024 + lane * 16, dst + c * 1024);
    }
  }
  if (tid < 128) sB1[tid] = be1[tid];
  else if (tid < 192) sB2[tid - 128] = be2[tid - 128];
  else if (tid < 224) sB3[tid - 192] = be3[tid - 192];

  int tile = blockIdx.x;
  us8 ra1[2], ra2[2];      // atom bf16 frags (raw)
  float4 rb[2][2];         // bond f32 raw
  int ia1n[2], ia2n[2];    // indices for NEXT tile
  int slotc = 0;           // CSR slot for this thread's row (tid<128), current tile

  // ---- prologue: gather tile0; indices for tile0+G
#pragma unroll
  for (int t = 0; t < 2; ++t) {
    const int e = tile * 128 + esub + t * 16;
    const int ia1 = a1p[e], ia2 = a2p[e];
    ra1[t] = *(const us8*)(atoms_bf + (size_t)ia1 * 32 + q * 8);
    ra2[t] = *(const us8*)(atoms_bf + (size_t)ia2 * 32 + q * 8);
    const float* bp = bonds + (size_t)e * 32 + q * 8;
    rb[t][0] = *(const float4*)(bp);
    rb[t][1] = *(const float4*)(bp + 4);
  }
  if (FAST && tid < 128) slotc = pos[tile * 128 + tid];
  {
    int tn = tile + EGRID; if (tn >= ETILES) tn = tile;
#pragma unroll
    for (int t = 0; t < 2; ++t) {
      const int e = tn * 128 + esub + t * 16;
      ia1n[t] = a1p[e]; ia2n[t] = a2p[e];
    }
  }
  __syncthreads();   // weights + biases staged

  for (; tile < ETILES; tile += EGRID) {
    // ---- convert current frags (frees ra/rb)
    bfrag8 xb0[2], xb1[2], xb2[2];
#pragma unroll
    for (int t = 0; t < 2; ++t) {
      xb0[t] = as_frag(ra1[t]);
      xb1[t] = as_frag(ra2[t]);
      xb2[t] = pack8(rb[t][0], rb[t][1]);
    }
    // ---- issue next tile's gathers (indices already resident), then next-next indices
    const int tn = (tile + EGRID < ETILES) ? tile + EGRID : tile;
#pragma unroll
    for (int t = 0; t < 2; ++t) {
      ra1[t] = *(const us8*)(atoms_bf + (size_t)ia1n[t] * 32 + q * 8);
      ra2[t] = *(const us8*)(atoms_bf + (size_t)ia2n[t] * 32 + q * 8);
      const int e = tn * 128 + esub + t * 16;
      const float* bp = bonds + (size_t)e * 32 + q * 8;
      rb[t][0] = *(const float4*)(bp);
      rb[t][1] = *(const float4*)(bp + 4);
    }
    int slotn = 0;
    if (FAST && tid < 128) slotn = pos[tn * 128 + tid];
    {
      int tnn = tile + 2 * EGRID; if (tnn >= ETILES) tnn = tn;
#pragma unroll
      for (int t = 0; t < 2; ++t) {
        const int e = tnn * 128 + esub + t * 16;
        ia1n[t] = a1p[e]; ia2n[t] = a2p[e];
      }
    }

    // ---- GEMM1: h1^T[128][16x2] = We1^T[128x96] @ x^T ----
#pragma unroll
    for (int rt = 0; rt < 8; ++rt) {
      const unsigned short* wa = &sW[(q * 128 + rt * 16 + cl) * 8];
      bfrag8 w0 = *(const bfrag8*)(wa);
      bfrag8 w1 = *(const bfrag8*)(wa + 4096);
      bfrag8 w2 = *(const bfrag8*)(wa + 8192);
      f32x4 acc[2];
      acc[0] = (f32x4){0.f, 0.f, 0.f, 0.f};
      acc[1] = (f32x4){0.f, 0.f, 0.f, 0.f};
#pragma unroll
      for (int t = 0; t < 2; ++t) {
        acc[t] = mfma16(w0, xb0[t], acc[t]);
        acc[t] = mfma16(w1, xb1[t], acc[t]);
        acc[t] = mfma16(w2, xb2[t], acc[t]);
      }
      const int c0 = rt * 16 + q * 4;
#pragma unroll
      for (int t = 0; t < 2; ++t) {
        uint2 hv = pk4(fmaxf(acc[t][0] + sB1[c0 + 0], 0.f),
                       fmaxf(acc[t][1] + sB1[c0 + 1], 0.f),
                       fmaxf(acc[t][2] + sB1[c0 + 2], 0.f),
                       fmaxf(acc[t][3] + sB1[c0 + 3], 0.f));
        *(uint2*)&sH1[(esub + t * 16) * 136 + c0] = hv;
      }
    }
    __syncthreads();   // h1 complete

    // ---- GEMM2: h2^T[64][16x2] = We2^T[64x128] @ h1^T ----
    bfrag8 hb[4][2];
#pragma unroll
    for (int t = 0; t < 2; ++t) {
      const unsigned short* hr = &sH1[(esub + t * 16) * 136 + q * 8];
#pragma unroll
      for (int ks = 0; ks < 4; ++ks) hb[ks][t] = *(const bfrag8*)(hr + ks * 32);
    }
    __syncthreads();   // h1 reads done -> safe to overwrite as h2 / out-stage

    unsigned short* sH2 = sH1;   // stride 72, [0,9216)
#pragma unroll
    for (int rt = 0; rt < 4; ++rt) {
      f32x4 acc[2];
      acc[0] = (f32x4){0.f, 0.f, 0.f, 0.f};
      acc[1] = (f32x4){0.f, 0.f, 0.f, 0.f};
#pragma unroll
      for (int ks = 0; ks < 4; ++ks) {
        bfrag8 w = *(const bfrag8*)&sW[12288 + ks * 2048 + (q * 64 + rt * 16 + cl) * 8];
#pragma unroll
        for (int t = 0; t < 2; ++t) acc[t] = mfma16(w, hb[ks][t], acc[t]);
      }
      const int c0 = rt * 16 + q * 4;
#pragma unroll
      for (int t = 0; t < 2; ++t) {
        uint2 hv = pk4(fmaxf(acc[t][0] + sB2[c0 + 0], 0.f),
                       fmaxf(acc[t][1] + sB2[c0 + 1], 0.f),
                       fmaxf(acc[t][2] + sB2[c0 + 2], 0.f),
                       fmaxf(acc[t][3] + sB2[c0 + 3], 0.f));
        *(uint2*)&sH2[(esub + t * 16) * 72 + c0] = hv;
      }
    }
    __syncthreads();   // h2 complete

    // ---- GEMM3: out^T[32][16x2] = We3^T[32x64] @ h2^T ----
    bfrag8 gb0[2], gb1[2];
#pragma unroll
    for (int t = 0; t < 2; ++t) {
      const unsigned short* hr = &sH2[(esub + t * 16) * 72 + q * 8];
      gb0[t] = *(const bfrag8*)(hr);
      gb1[t] = *(const bfrag8*)(hr + 32);
    }
    unsigned short* sOut = sH1 + 9216;   // [128][40] shorts, dead region above h2
#pragma unroll
    for (int rt = 0; rt < 2; ++rt) {
      bfrag8 w0 = *(const bfrag8*)&sW[20480 + (q * 32 + rt * 16 + cl) * 8];
      bfrag8 w1 = *(const bfrag8*)&sW[20480 + 1024 + (q * 32 + rt * 16 + cl) * 8];
      const int c0 = rt * 16 + q * 4;
#pragma unroll
      for (int t = 0; t < 2; ++t) {
        f32x4 acc = {0.f, 0.f, 0.f, 0.f};
        acc = mfma16(w0, gb0[t], acc);
        acc = mfma16(w1, gb1[t], acc);
        const int e = tile * 128 + esub + t * 16;
        float4 o;
        o.x = acc[0] + sB3[c0 + 0];
        o.y = acc[1] + sB3[c0 + 1];
        o.z = acc[2] + sB3[c0 + 2];
        o.w = acc[3] + sB3[c0 + 3];
        *(float4*)(new_bonds + (size_t)e * 32 + c0) = o;
        if (FAST) {
          *(uint2*)&sOut[(esub + t * 16) * 40 + c0] =
              make_uint2(pk2(o.x, o.y), pk2(o.z, o.w));
        }
      }
    }
    if (FAST) {
      __syncthreads();   // out-stage complete (rows span waves)
      if (tid < 128) {
        const u32x4* src = (const u32x4*)&sOut[tid * 40];
        u32x4* dst = (u32x4*)(nb_bf + (size_t)slotc * 32);
#pragma unroll
        for (int k = 0; k < 4; ++k) dst[k] = src[k];   // 64B contiguous per thread
      }
      slotc = slotn;
    }
    __syncthreads();   // all LDS reads done -> next tile may overwrite sH1/sH2/sOut
  }
}

// ---------------- Gather (fast): sequential segmented mean over CSR-ordered bf16 rows ----
__global__ __launch_bounds__(256, 8) void gather_seq(
    const int* __restrict__ off, const unsigned short* __restrict__ nb_bf,
    unsigned short* __restrict__ mean_bf) {
  const int gt = blockIdx.x * 256 + threadIdx.x;   // NN*8
  const int n = gt >> 3, sl = gt & 7;              // 8 B slice (4 bf16) per thread
  const int o0 = off[n], o1 = off[n + 1];
  const int deg = o1 - o0;
  float s0 = 0.f, s1 = 0.f, s2 = 0.f, s3 = 0.f;
  const unsigned short* p = nb_bf + (size_t)o0 * 32 + sl * 4;
  int i = 0;
  for (; i + 1 < deg; i += 2) {
    uint2 a = *(const uint2*)(p);
    uint2 b = *(const uint2*)(p + 32);
    p += 64;
    s0 += bl(a.x) + bl(b.x); s1 += bh(a.x) + bh(b.x);
    s2 += bl(a.y) + bl(b.y); s3 += bh(a.y) + bh(b.y);
  }
  if (i < deg) {
    uint2 a = *(const uint2*)(p);
    s0 += bl(a.x); s1 += bh(a.x); s2 += bl(a.y); s3 += bh(a.y);
  }
  const float inv = 1.0f / fmaxf((float)deg, 1.0f);
  *(uint2*)(mean_bf + (size_t)n * 32 + sl * 4) =
      make_uint2(pk2(s0 * inv, s1 * inv), pk2(s2 * inv, s3 * inv));
}

// ---------------- Gather (fallback): random rows via csr ----------------
__global__ __launch_bounds__(256, 8) void gather_rand(
    const int* __restrict__ off, const int* __restrict__ csr,
    const float* __restrict__ new_bonds, float* __restrict__ mean_f32) {
  const int tid = blockIdx.x * 256 + threadIdx.x;   // NN*8
  const int n = tid >> 3, sl = tid & 7;             // 16 B slice per thread
  const int o0 = off[n], o1 = off[n + 1];
  float4 s0 = {0.f, 0.f, 0.f, 0.f}, s1 = {0.f, 0.f, 0.f, 0.f};
  int i = o0;
  for (; i + 1 < o1; i += 2) {
    const int ea = csr[i], eb = csr[i + 1];
    float4 a = *(const float4*)(new_bonds + (size_t)ea * 32 + sl * 4);
    float4 b = *(const float4*)(new_bonds + (size_t)eb * 32 + sl * 4);
    s0.x += a.x; s0.y += a.y; s0.z += a.z; s0.w += a.w;
    s1.x += b.x; s1.y += b.y; s1.z += b.z; s1.w += b.w;
  }
  if (i < o1) {
    const int ea = csr[i];
    float4 a = *(const float4*)(new_bonds + (size_t)ea * 32 + sl * 4);
    s0.x += a.x; s0.y += a.y; s0.z += a.z; s0.w += a.w;
  }
  const float inv = 1.0f / fmaxf((float)(o1 - o0), 1.0f);
  float4 m;
  m.x = (s0.x + s1.x) * inv;
  m.y = (s0.y + s1.y) * inv;
  m.z = (s0.z + s1.z) * inv;
  m.w = (s0.w + s1.w) * inv;
  *(float4*)(mean_f32 + (size_t)n * 32 + sl * 4) = m;
}

// ---------------- Node MLP: persistent, 64 nodes/tile, streaming inputs -------
// MODE 1: mean_src = bf16[NN*32]; MODE 0: mean_src = f32[NN*32]
template <int MODE>
__global__ __launch_bounds__(256, 4) void node_mlp(
    const unsigned short* __restrict__ atoms_bf,
    const float* __restrict__ bv1, const float* __restrict__ bv2, const float* __restrict__ bv3,
    const unsigned short* __restrict__ wpack,
    const void* __restrict__ mean_src, float* __restrict__ new_atoms) {
  __shared__ unsigned short sW[18432];          // Wv1p[8192] Wv2p[8192] Wv3p[2048]
  __shared__ float sB1[128], sB2[64], sB3[32];
  __shared__ unsigned short sV[64 * 72];        // v_in [64][64] pad->72; reused as h2
  __shared__ unsigned short sH1[64 * 136];

  const int tid = threadIdx.x;
  const int lane = tid & 63, wv = tid >> 6;
  const int cl = lane & 15, q = lane >> 4;
  const int nl = tid >> 2, l4 = tid & 3;

  {
    const uint4* src = (const uint4*)wpack;
    uint4* dst = (uint4*)sW;
#pragma unroll
    for (int i = 0; i < 9; ++i) dst[tid + i * 256] = src[tid + i * 256];
  }
  if (tid < 128) sB1[tid] = bv1[tid];
  if (tid < 64) sB2[tid] = bv2[tid];
  if (tid < 32) sB3[tid] = bv3[tid];

  for (int n0 = blockIdx.x * 64; n0 < NN; n0 += NGRID * 64) {
    __syncthreads();   // weights staged / previous tile's LDS reads complete

    // stage v tile: cols [0,32) = mean, [32,64) = atoms (bf16 copy)
    {
      const int n = n0 + nl;
      if (n < NN) {
        if (l4 < 2) {
          if (MODE == 1) {
            const unsigned short* mp = (const unsigned short*)mean_src + (size_t)n * 32 + l4 * 16;
            *(us8*)&sV[nl * 72 + l4 * 16] = *(const us8*)(mp);
            *(us8*)&sV[nl * 72 + l4 * 16 + 8] = *(const us8*)(mp + 8);
          } else {
            const float* sp = (const float*)mean_src + (size_t)n * 32 + l4 * 16;
            float4 a = *(const float4*)(sp);
            float4 b = *(const float4*)(sp + 4);
            float4 c = *(const float4*)(sp + 8);
            float4 d = *(const float4*)(sp + 12);
            uint4 o0, o1;
            o0.x = pk2(a.x, a.y); o0.y = pk2(a.z, a.w);
            o0.z = pk2(b.x, b.y); o0.w = pk2(b.z, b.w);
            o1.x = pk2(c.x, c.y); o1.y = pk2(c.z, c.w);
            o1.z = pk2(d.x, d.y); o1.w = pk2(d.z, d.w);
            *(uint4*)&sV[nl * 72 + l4 * 16] = o0;
            *(uint4*)&sV[nl * 72 + l4 * 16 + 8] = o1;
          }
        } else {
          const unsigned short* ap = atoms_bf + (size_t)n * 32 + (l4 - 2) * 16;
          *(us8*)&sV[nl * 72 + 32 + (l4 - 2) * 16] = *(const us8*)(ap);
          *(us8*)&sV[nl * 72 + 32 + (l4 - 2) * 16 + 8] = *(const us8*)(ap + 8);
        }
      } else {
        us8 z = {0, 0, 0, 0, 0, 0, 0, 0};
        *(us8*)&sV[nl * 72 + l4 * 16] = z;
        *(us8*)&sV[nl * 72 + l4 * 16 + 8] = z;
      }
    }
    __syncthreads();

    const int nt = wv * 16;
    const int ng = n0 + nt + cl;

    // ---- GEMM1: K=64 ----
    bfrag8 vb0 = *(const bfrag8*)&sV[(nt + cl) * 72 + q * 8];
    bfrag8 vb1 = *(const bfrag8*)&sV[(nt + cl) * 72 + 32 + q * 8];
#pragma unroll
    for (int rt = 0; rt < 8; ++rt) {
      f32x4 acc = {0.f, 0.f, 0.f, 0.f};
      acc = mfma16(*(const bfrag8*)&sW[(q * 128 + rt * 16 + cl) * 8], vb0, acc);
      acc = mfma16(*(const bfrag8*)&sW[4096 + (q * 128 + rt * 16 + cl) * 8], vb1, acc);
      const int c0 = rt * 16 + q * 4;
      uint2 hv = pk4(fmaxf(acc[0] + sB1[c0 + 0], 0.f),
                     fmaxf(acc[1] + sB1[c0 + 1], 0.f),
                     fmaxf(acc[2] + sB1[c0 + 2], 0.f),
                     fmaxf(acc[3] + sB1[c0 + 3], 0.f));
      *(uint2*)&sH1[(nt + cl) * 136 + c0] = hv;
    }
    __syncthreads();

    // ---- GEMM2: K=128 ----
    bfrag8 hb[4];
    {
      const unsigned short* hr = &sH1[(nt + cl) * 136 + q * 8];
#pragma unroll
      for (int ks = 0; ks < 4; ++ks) hb[ks] = *(const bfrag8*)(hr + ks * 32);
    }
    __syncthreads();   // h1 reads done -> overwrite sV as h2
#pragma unroll
    for (int rt = 0; rt < 4; ++rt) {
      f32x4 acc = {0.f, 0.f, 0.f, 0.f};
#pragma unroll
      for (int ks = 0; ks < 4; ++ks)
        acc = mfma16(*(const bfrag8*)&sW[8192 + ks * 2048 + (q * 64 + rt * 16 + cl) * 8], hb[ks], acc);
      const int c0 = rt * 16 + q * 4;
      uint2 hv = pk4(fmaxf(acc[0] + sB2[c0 + 0], 0.f),
                     fmaxf(acc[1] + sB2[c0 + 1], 0.f),
                     fmaxf(acc[2] + sB2[c0 + 2], 0.f),
                     fmaxf(acc[3] + sB2[c0 + 3], 0.f));
      *(uint2*)&sV[(nt + cl) * 72 + c0] = hv;   // reuse sV as h2
    }
    __syncthreads();

    // ---- GEMM3: K=64, no relu ----
    bfrag8 gb0 = *(const bfrag8*)&sV[(nt + cl) * 72 + q * 8];
    bfrag8 gb1 = *(const bfrag8*)&sV[(nt + cl) * 72 + 32 + q * 8];
    if (ng < NN) {
      float* outp = new_atoms + (size_t)ng * 32;
#pragma unroll
      for (int rt = 0; rt < 2; ++rt) {
        f32x4 acc = {0.f, 0.f, 0.f, 0.f};
        acc = mfma16(*(const bfrag8*)&sW[16384 + (q * 32 + rt * 16 + cl) * 8], gb0, acc);
        acc = mfma16(*(const bfrag8*)&sW[16384 + 1024 + (q * 32 + rt * 16 + cl) * 8], gb1, acc);
        const int c0 = rt * 16 + q * 4;
        float4 o;
        o.x = acc[0] + sB3[c0 + 0];
        o.y = acc[1] + sB3[c0 + 1];
        o.z = acc[2] + sB3[c0 + 2];
        o.w = acc[3] + sB3[c0 + 3];
        *(float4*)(outp + c0) = o;
      }
    }
  }
}

extern "C" void kernel_launch(void* const* d_in, const int* in_sizes, int n_in,
                              void* d_out, int out_size, void* d_ws, size_t ws_size,
                              hipStream_t stream) {
  const float* bonds = (const float*)d_in[0];
  const int* a1 = (const int*)d_in[1];
  const int* a2 = (const int*)d_in[2];
  const float* atoms = (const float*)d_in[3];
  const float* We1 = (const float*)d_in[4];
  const float* be1 = (const float*)d_in[5];
  const float* We2 = (const float*)d_in[6];
  const float* be2 = (const float*)d_in[7];
  const float* We3 = (const float*)d_in[8];
  const float* be3 = (const float*)d_in[9];
  const float* Wv1 = (const float*)d_in[10];
  const float* bv1 = (const float*)d_in[11];
  const float* Wv2 = (const float*)d_in[12];
  const float* bv2 = (const float*)d_in[13];
  const float* Wv3 = (const float*)d_in[14];
  const float* bv3 = (const float*)d_in[15];

  float* out = (float*)d_out;
  float* new_atoms = out;                       // [NN*32]; fallback: also mean_f32 scratch
  float* new_bonds = out + (size_t)NN * 32;     // [NE*32]

  char* ws = (char*)d_ws;
  int* cnt    = (int*)(ws + 0);                 // [NN], reused as fill cursor
  int* off    = (int*)(ws + 400000);            // [NN+1]
  int* bsum   = (int*)(ws + 800016);            // [512]
  unsigned short* wp = (unsigned short*)(ws + 802064);        // packed bf16 weights (81920 B)
  int* poscsr = (int*)(ws + 883984);            // [NE] pos (fast) or csr (fallback)
  unsigned short* atoms_bf = (unsigned short*)(ws + 7283984); // [NN*32] bf16 (6.4 MB)
  unsigned short* mean_bf  = (unsigned short*)(ws + 13683984); // [NN*32] bf16 (fast only)
  unsigned short* nb_bf    = (unsigned short*)(ws + 20083984); // [NE*32] bf16 (fast only)

  const int fast = (ws_size >= (size_t)122483984) ? 1 : 0;

  hipMemsetAsync(cnt, 0, (size_t)NN * 4, stream);

  prep<<<9535, 256, 0, stream>>>(atoms, atoms_bf, a2, cnt,
                                 We1, We2, We3, Wv1, Wv2, Wv3, wp);

  scan_blocks<<<NB_SCAN, 256, 0, stream>>>(cnt, off, bsum);
  scan_finalize<<<NB_SCAN, 256, 0, stream>>>(off, bsum, cnt);   // cursor := cnt
  fill_k<<<(NE + 255) / 256, 256, 0, stream>>>(a2, cnt, poscsr, fast);

  if (fast) {
    edge_kernel<1><<<EGRID, 256, 0, stream>>>(bonds, a1, a2, atoms_bf, be1, be2, be3, wp,
                                              new_bonds, poscsr, nb_bf);
    gather_seq<<<NN * 8 / 256, 256, 0, stream>>>(off, nb_bf, mean_bf);
    node_mlp<1><<<NGRID, 256, 0, stream>>>(atoms_bf, bv1, bv2, bv3, wp + 22528,
                                           mean_bf, new_atoms);
  } else {
    edge_kernel<0><<<EGRID, 256, 0, stream>>>(bonds, a1, a2, atoms_bf, be1, be2, be3, wp,
                                              new_bonds, nullptr, nullptr);
    gather_rand<<<NN * 8 / 256, 256, 0, stream>>>(off, poscsr, new_bonds, new_atoms);
    node_mlp<0><<<NGRID, 256, 0, stream>>>(atoms_bf, bv1, bv2, bv3, wp + 22528,
                                           new_atoms, new_atoms);
  }
}